// Round 11
// baseline (231.203 us; speedup 1.0000x reference)
//
#include <hip/hip_runtime.h>
#include <hip/hip_bf16.h>
#include <math.h>

#define S_LEN 4096
#define DMODEL 2048
#define HEADD 128

typedef __attribute__((ext_vector_type(8))) short short8;
typedef __attribute__((ext_vector_type(4))) float floatx4;

__device__ __forceinline__ short f2bs(float f) {
  __hip_bfloat16 h = __float2bfloat16(f);
  short s; __builtin_memcpy(&s, &h, 2); return s;
}
__device__ __forceinline__ int pkbf(float a, float b) {  // (lo=a, hi=b) bf16 pair
  return (int)(((unsigned)(unsigned short)f2bs(b) << 16) |
               (unsigned)(unsigned short)f2bs(a));
}

// ---- Kernel 1: convert Wq,Wk,Wv (fp32 [128][2048] each) -> wc bf16 [384][2048]
__global__ __launch_bounds__(256) void convw_kernel(const float* __restrict__ wq,
                                                    const float* __restrict__ wk,
                                                    const float* __restrict__ wv,
                                                    short* __restrict__ wc) {
  const int per = 128 * 2048;
  int e = (blockIdx.x * blockDim.x + threadIdx.x) * 4;
  const float* src = (e < per) ? wq : (e < 2 * per) ? wk : wv;
  int off = e & (per - 1);
  float4 v = *(const float4*)(src + off);
  short4 r;
  r.x = f2bs(v.x); r.y = f2bs(v.y); r.z = f2bs(v.z); r.w = f2bs(v.w);
  *(short4*)(wc + e) = r;
}

// ---- Kernel 2: projection GEMM  C[8192][384] = X[8192][2048] @ Wc^T
// grid (256 m-blocks of 32) x (4 n-quarters of 96); 256 thr = 4 waves =
// (m-sub 0/1) x (n-sub 0/1), each wave 16 rows x 48 cols (acc[3]=12 fp32).
// 4 blocks/CU = 16 waves/CU. X prefetched 2 deep, W 1 deep -> ~4x latency
// tolerance vs R10. X re-read 4x is L3-absorbed; W (1.5MB) L2-resident.
__global__ __launch_bounds__(256, 4) void proj_kernel(const float* __restrict__ x,
                                                      const short* __restrict__ wc,
                                                      short* __restrict__ qm,
                                                      short* __restrict__ kb,
                                                      short* __restrict__ vt) {
  const int w = threadIdx.x >> 6;
  const int lane = threadIdx.x & 63;
  const int lo = lane & 15, g = lane >> 4;
  const int m0 = blockIdx.x * 32 + (w >> 1) * 16;
  const int n0 = blockIdx.y * 96 + (w & 1) * 48;

  const float* xrow = x + (size_t)(m0 + lo) * DMODEL;
  const short* wrow = wc + (size_t)(n0 + lo) * DMODEL;

  floatx4 acc[3];
#pragma unroll
  for (int t = 0; t < 3; ++t) acc[t] = floatx4{0.f, 0.f, 0.f, 0.f};

  // prefetch: X 2 deep, W 1 deep
  float4 a0 = *(const float4*)(xrow + g * 8);
  float4 a1 = *(const float4*)(xrow + g * 8 + 4);
  float4 b0 = *(const float4*)(xrow + 32 + g * 8);
  float4 b1 = *(const float4*)(xrow + 32 + g * 8 + 4);
  short8 wf[3];
#pragma unroll
  for (int t = 0; t < 3; ++t) wf[t] = *(const short8*)(wrow + t * 16 * DMODEL + g * 8);

#pragma unroll 1
  for (int k = 0; k < DMODEL; k += 32) {
    const int k1 = (k + 32 < DMODEL) ? k + 32 : 0;
    const int k2 = (k + 64 < DMODEL) ? k + 64 : 0;
    float4 c0 = *(const float4*)(xrow + k2 + g * 8);
    float4 c1 = *(const float4*)(xrow + k2 + g * 8 + 4);
    short8 wn[3];
#pragma unroll
    for (int t = 0; t < 3; ++t) wn[t] = *(const short8*)(wrow + t * 16 * DMODEL + k1 + g * 8);

    short8 af;
    af[0] = f2bs(a0.x); af[1] = f2bs(a0.y); af[2] = f2bs(a0.z); af[3] = f2bs(a0.w);
    af[4] = f2bs(a1.x); af[5] = f2bs(a1.y); af[6] = f2bs(a1.z); af[7] = f2bs(a1.w);
#pragma unroll
    for (int t = 0; t < 3; ++t)
      acc[t] = __builtin_amdgcn_mfma_f32_16x16x32_bf16(af, wf[t], acc[t], 0, 0, 0);

    a0 = b0; a1 = b1; b0 = c0; b1 = c1;
    wf[0] = wn[0]; wf[1] = wn[1]; wf[2] = wn[2];
  }

#pragma unroll
  for (int t = 0; t < 3; ++t) {
    int n = n0 + t * 16 + lo;
#pragma unroll
    for (int j = 0; j < 4; ++j) {
      int m = m0 + g * 4 + j;
      if (n < HEADD) {
        qm[(size_t)m * HEADD + n] = f2bs(acc[t][j] * 0.125f);   // fold 1/sqrt(64)
      } else if (n < 2 * HEADD) {
        kb[(size_t)m * HEADD + (n - HEADD)] = f2bs(acc[t][j]);
      } else {
        int h = n - 2 * HEADD;
        int bb = m >> 12, s = m & (S_LEN - 1);
        vt[((size_t)bb * HEADD + h) * S_LEN + s] = f2bs(acc[t][j]);
      }
    }
  }
}

// ---- Kernel 3: LDS-staged flash attention -> fp32 atomic partial accumulators
// (unchanged from R10: 512 blocks = 128 qblk x 4 kv-quarters, 8 waves,
// K/V LDS dbuf 1 barrier/step, swapped QK^T + shfl transpose, no-max softmax)
__global__ __launch_bounds__(512, 4) void attn_kernel(const short* __restrict__ qm,
                                                      const short* __restrict__ kb,
                                                      const short* __restrict__ vt,
                                                      float* __restrict__ ao,
                                                      float* __restrict__ al) {
  const int tid = threadIdx.x;
  const int w = tid >> 6;
  const int lane = tid & 63;
  const int lo = lane & 15, g = lane >> 4;
  const int qs = w >> 1;            // q-subtile 0..3
  const int s = w & 1;              // attn stream
  const int id = blockIdx.x;
  const int qblk = id >> 2;         // 0..127 global (b = qblk>>6)
  const int ksp = id & 3;           // kv quarter (1024 kv, 32 steps)
  const int b = qblk >> 6;
  const int kv_base = ksp * 1024;

  __shared__ short kt[2][32][136];  // K tile (pad 8)
  __shared__ short vl[2][128][40];  // V^T tile (pad 8)

  const int kr = tid >> 4, kc = tid & 15;
  const int vh = tid >> 2, vc = tid & 3;
  const short* kS = kb + (size_t)b * S_LEN * HEADD;
  const short* vS = vt + (size_t)b * HEADD * S_LEN;

  const int rowq = qblk * 64 + qs * 16;
  const short* qrow = qm + (size_t)(rowq + lo) * HEADD + s * 64;
  const short8 qf0 = *(const short8*)(qrow + g * 8);
  const short8 qf1 = *(const short8*)(qrow + 32 + g * 8);

  floatx4 acc[8];
#pragma unroll
  for (int n = 0; n < 8; ++n) acc[n] = floatx4{0.f, 0.f, 0.f, 0.f};
  float lx = 0.f;

  const int gA = (g & 1) * 2;
  const int idx0 = lo + 16 * gA, idx1 = idx0 + 16;
  const bool hi = (g >= 2);

  {
    int4 k0 = *(const int4*)(kS + (size_t)(kv_base + kr) * HEADD + kc * 8);
    int4 v0 = *(const int4*)(vS + (size_t)vh * S_LEN + kv_base + vc * 8);
    *(int4*)(&kt[0][kr][kc * 8]) = k0;
    *(int4*)(&vl[0][vh][vc * 8]) = v0;
  }
  __syncthreads();

  int cur = 0;
#pragma unroll 1
  for (int it = 0; it < 32; ++it) {
    int4 knx, vnx;
    if (it + 1 < 32) {
      const int kvn = kv_base + (it + 1) * 32;
      knx = *(const int4*)(kS + (size_t)(kvn + kr) * HEADD + kc * 8);
      vnx = *(const int4*)(vS + (size_t)vh * S_LEN + kvn + vc * 8);
    }

    floatx4 z = floatx4{0.f, 0.f, 0.f, 0.f};
    const short* kp0 = &kt[cur][lo][s * 64 + g * 8];
    short8 a00 = *(const short8*)(kp0);
    short8 a01 = *(const short8*)(kp0 + 32);
    floatx4 u0 = __builtin_amdgcn_mfma_f32_16x16x32_bf16(a00, qf0, z, 0, 0, 0);
    floatx4 T0 = __builtin_amdgcn_mfma_f32_16x16x32_bf16(a01, qf1, u0, 0, 0, 0);
    const short* kp1 = &kt[cur][16 + lo][s * 64 + g * 8];
    short8 a10 = *(const short8*)(kp1);
    short8 a11 = *(const short8*)(kp1 + 32);
    floatx4 u1 = __builtin_amdgcn_mfma_f32_16x16x32_bf16(a10, qf0, z, 0, 0, 0);
    floatx4 T1 = __builtin_amdgcn_mfma_f32_16x16x32_bf16(a11, qf1, u1, 0, 0, 0);

    float p0 = __expf(T0[0]), p1 = __expf(T0[1]), p2 = __expf(T0[2]), p3 = __expf(T0[3]);
    float p4 = __expf(T1[0]), p5 = __expf(T1[1]), p6 = __expf(T1[2]), p7 = __expf(T1[3]);

    float lp = ((p0 + p1) + (p2 + p3)) + ((p4 + p5) + (p6 + p7));
    lp += __shfl_xor(lp, 16);
    lp += __shfl_xor(lp, 32);
    lx += lp;

    int c00 = pkbf(p0, p1), c01 = pkbf(p2, p3);
    int c10 = pkbf(p4, p5), c11 = pkbf(p6, p7);
    int t0a = __shfl(c00, idx0), t0b = __shfl(c01, idx0);
    int t0c = __shfl(c00, idx1), t0d = __shfl(c01, idx1);
    int t1a = __shfl(c10, idx0), t1b = __shfl(c11, idx0);
    int t1c = __shfl(c10, idx1), t1d = __shfl(c11, idx1);
    int w0 = hi ? t1a : t0a, w1 = hi ? t1b : t0b;
    int w2 = hi ? t1c : t0c, w3 = hi ? t1d : t0d;
    short8 pa;
    { int4 tmp = {w0, w1, w2, w3}; __builtin_memcpy(&pa, &tmp, 16); }

#pragma unroll
    for (int n = 0; n < 8; ++n) {
      short8 vf = *(const short8*)(&vl[cur][n * 16 + lo][g * 8]);
      acc[n] = __builtin_amdgcn_mfma_f32_16x16x32_bf16(pa, vf, acc[n], 0, 0, 0);
    }

    if (it + 1 < 32) {
      *(int4*)(&kt[cur ^ 1][kr][kc * 8]) = knx;
      *(int4*)(&vl[cur ^ 1][vh][vc * 8]) = vnx;
    }
    __syncthreads();
    cur ^= 1;
  }

  float* aw = ao + ((size_t)s * 8192 + rowq) * 128;
#pragma unroll
  for (int n = 0; n < 8; ++n)
#pragma unroll
    for (int j = 0; j < 4; ++j)
      atomicAdd(&aw[(size_t)(g * 4 + j) * 128 + n * 16 + lo], acc[n][j]);
  if (g == 0)
    atomicAdd(&al[(size_t)s * 8192 + rowq + lo], lx);
}

// ---- Kernel 4: normalize + diff combine + RMSNorm -> out
__global__ __launch_bounds__(256) void merge_kernel(const float* __restrict__ ao,
                                                    const float* __restrict__ al,
                                                    const float* __restrict__ lq1,
                                                    const float* __restrict__ lq2,
                                                    const float* __restrict__ lk1,
                                                    const float* __restrict__ lk2,
                                                    const float* __restrict__ rmsw,
                                                    float* __restrict__ out) {
  const int tid = threadIdx.x;
  const int gr = blockIdx.x * 8 + (tid >> 5);
  const int c0 = (tid & 31) * 4;

  float a1s = 0.f, a2s = 0.f;
  for (int i = 0; i < 64; ++i) {
    a1s = fmaf(lq1[i], lk1[i], a1s);
    a2s = fmaf(lq2[i], lk2[i], a2s);
  }
  const float lam = __expf(a1s) - __expf(a2s) + 0.7836057665316245f;

  float4 o1 = *(const float4*)(ao + ((size_t)0 * 8192 + gr) * 128 + c0);
  float4 o2 = *(const float4*)(ao + ((size_t)1 * 8192 + gr) * 128 + c0);
  const float iL1 = 1.f / al[gr];
  const float iL2 = 1.f / al[8192 + gr];

  float v[4];
  v[0] = o1.x * iL1 - lam * (o2.x * iL2);
  v[1] = o1.y * iL1 - lam * (o2.y * iL2);
  v[2] = o1.z * iL1 - lam * (o2.z * iL2);
  v[3] = o1.w * iL1 - lam * (o2.w * iL2);
  float ssq = v[0] * v[0] + v[1] * v[1] + v[2] * v[2] + v[3] * v[3];
#pragma unroll
  for (int d = 1; d < 32; d <<= 1) ssq += __shfl_xor(ssq, d);
  const float rr = rsqrtf(ssq * (1.f / 128.f) + 1.1920928955078125e-07f);

  float4 wv4 = *(const float4*)(rmsw + c0);
  float4 r4;
  r4.x = 0.21639423346837554f * v[0] * rr * wv4.x;
  r4.y = 0.21639423346837554f * v[1] * rr * wv4.y;
  r4.z = 0.21639423346837554f * v[2] * rr * wv4.z;
  r4.w = 0.21639423346837554f * v[3] * rr * wv4.w;
  *(float4*)(out + (size_t)gr * 128 + c0) = r4;
}

extern "C" void kernel_launch(void* const* d_in, const int* in_sizes, int n_in,
                              void* d_out, int out_size, void* d_ws, size_t ws_size,
                              hipStream_t stream) {
  const float* x   = (const float*)d_in[0];
  const float* wq  = (const float*)d_in[1];
  const float* wk  = (const float*)d_in[2];
  const float* wv  = (const float*)d_in[3];
  const float* lq1 = (const float*)d_in[4];
  const float* lq2 = (const float*)d_in[5];
  const float* lk1 = (const float*)d_in[6];
  const float* lk2 = (const float*)d_in[7];
  const float* rw  = (const float*)d_in[8];
  float* out = (float*)d_out;

  char* ws = (char*)d_ws;
  short* qm = (short*)(ws);                    // 2 MB (q pre-scaled 0.125)
  short* kb = (short*)(ws + (2u << 20));       // 2 MB
  short* vt = (short*)(ws + (4u << 20));       // 2 MB (V transposed [b][h][s])
  short* wc = (short*)(ws + (6u << 20));       // 1.5 MB
  float* ao = (float*)(ws + (8u << 20));       // 8 MB fp32 O accumulators [2][8192][128]
  float* al = (float*)(ws + (8u << 20) + 8388608u);  // 64 KB fp32 l accumulators [2][8192]

  hipMemsetAsync(ws + (8u << 20), 0, 8388608u + 65536u, stream);

  convw_kernel<<<768, 256, 0, stream>>>(wq, wk, wv, wc);
  proj_kernel<<<dim3(256, 4), 256, 0, stream>>>(x, wc, qm, kb, vt);
  attn_kernel<<<512, 512, 0, stream>>>(qm, kb, vt, ao, al);
  merge_kernel<<<1024, 256, 0, stream>>>(ao, al, lq1, lq2, lk1, lk2, rw, out);
}

// Round 12
// 216.643 us; speedup vs baseline: 1.0672x; 1.0672x over previous
//
#include <hip/hip_runtime.h>
#include <hip/hip_bf16.h>
#include <math.h>

#define S_LEN 4096
#define DMODEL 2048
#define HEADD 128

typedef __attribute__((ext_vector_type(8))) short short8;
typedef __attribute__((ext_vector_type(4))) float floatx4;

__device__ __forceinline__ short f2bs(float f) {
  __hip_bfloat16 h = __float2bfloat16(f);
  short s; __builtin_memcpy(&s, &h, 2); return s;
}
__device__ __forceinline__ int pkbf(float a, float b) {  // (lo=a, hi=b) bf16 pair
  return (int)(((unsigned)(unsigned short)f2bs(b) << 16) |
               (unsigned)(unsigned short)f2bs(a));
}

// ---- Kernel 0: convert X fp32 [8192][2048] -> xb bf16 (read 64MB, write 32MB)
__global__ __launch_bounds__(256) void convx_kernel(const float* __restrict__ x,
                                                    short* __restrict__ xb) {
  size_t e = ((size_t)blockIdx.x * 256 + threadIdx.x) * 8;
  float4 v0 = *(const float4*)(x + e);
  float4 v1 = *(const float4*)(x + e + 4);
  short8 r;
  r[0] = f2bs(v0.x); r[1] = f2bs(v0.y); r[2] = f2bs(v0.z); r[3] = f2bs(v0.w);
  r[4] = f2bs(v1.x); r[5] = f2bs(v1.y); r[6] = f2bs(v1.z); r[7] = f2bs(v1.w);
  *(short8*)(xb + e) = r;
}

// ---- Kernel 1: convert Wq,Wk,Wv (fp32 [128][2048] each) -> wc bf16 [384][2048]
__global__ __launch_bounds__(256) void convw_kernel(const float* __restrict__ wq,
                                                    const float* __restrict__ wk,
                                                    const float* __restrict__ wv,
                                                    short* __restrict__ wc) {
  const int per = 128 * 2048;
  int e = (blockIdx.x * blockDim.x + threadIdx.x) * 4;
  const float* src = (e < per) ? wq : (e < 2 * per) ? wk : wv;
  int off = e & (per - 1);
  float4 v = *(const float4*)(src + off);
  short4 r;
  r.x = f2bs(v.x); r.y = f2bs(v.y); r.z = f2bs(v.z); r.w = f2bs(v.w);
  *(short4*)(wc + e) = r;
}

// ---- Kernel 2a: bf16 projection GEMM, XCD-pinned.
// grid 768 1D: xcd=id&7 owns X rows [xcd*1024, +1024) = 4MB bf16 = its L2.
// loc=id>>3: mloc=loc/3 (32 m-blocks of 32 rows), nq=loc%3 (128-col band ->
// whole block writes exactly one of q/k/v). 4 waves = (m-sub x n-sub),
// wave = 16 rows x 64 cols (acc[4]). k-step 64, full 2-step named prefetch.
// ~118 regs < 170 cap at (256,3); 3 blocks/CU = 12 waves/CU.
__global__ __launch_bounds__(256, 3) void proj_bf16_kernel(const short* __restrict__ xb,
                                                           const short* __restrict__ wc,
                                                           short* __restrict__ qm,
                                                           short* __restrict__ kb,
                                                           short* __restrict__ vt) {
  const int w = threadIdx.x >> 6;
  const int lane = threadIdx.x & 63;
  const int lo = lane & 15, g = lane >> 4;
  const int id = blockIdx.x;
  const int xcd = id & 7, loc = id >> 3;       // loc 0..95
  const int mloc = loc / 3, nq = loc - mloc * 3;
  const int m0 = (xcd * 32 + mloc) * 32 + (w >> 1) * 16;
  const int n0 = nq * 128 + (w & 1) * 64;

  const short* xrow = xb + (size_t)(m0 + lo) * DMODEL + g * 8;
  const short* wrow = wc + (size_t)(n0 + lo) * DMODEL + g * 8;  // t stride 16*DMODEL

  floatx4 acc[4];
#pragma unroll
  for (int t = 0; t < 4; ++t) acc[t] = floatx4{0.f, 0.f, 0.f, 0.f};

  // prefetch k=0 and k=32
  short8 aA = *(const short8*)(xrow);
  short8 aB = *(const short8*)(xrow + 32);
  short8 wA0 = *(const short8*)(wrow);
  short8 wA1 = *(const short8*)(wrow + 16 * DMODEL);
  short8 wA2 = *(const short8*)(wrow + 32 * DMODEL);
  short8 wA3 = *(const short8*)(wrow + 48 * DMODEL);
  short8 wB0 = *(const short8*)(wrow + 32);
  short8 wB1 = *(const short8*)(wrow + 16 * DMODEL + 32);
  short8 wB2 = *(const short8*)(wrow + 32 * DMODEL + 32);
  short8 wB3 = *(const short8*)(wrow + 48 * DMODEL + 32);

#pragma unroll 1
  for (int k = 0; k < DMODEL; k += 64) {
    const int k1 = (k + 64 < DMODEL) ? k + 64 : 0;
    const int k2 = k1 + 32;
    short8 aC = *(const short8*)(xrow + k1);
    short8 aD = *(const short8*)(xrow + k2);
    short8 wC0 = *(const short8*)(wrow + k1);
    short8 wC1 = *(const short8*)(wrow + 16 * DMODEL + k1);
    short8 wC2 = *(const short8*)(wrow + 32 * DMODEL + k1);
    short8 wC3 = *(const short8*)(wrow + 48 * DMODEL + k1);
    short8 wD0 = *(const short8*)(wrow + k2);
    short8 wD1 = *(const short8*)(wrow + 16 * DMODEL + k2);
    short8 wD2 = *(const short8*)(wrow + 32 * DMODEL + k2);
    short8 wD3 = *(const short8*)(wrow + 48 * DMODEL + k2);

    acc[0] = __builtin_amdgcn_mfma_f32_16x16x32_bf16(aA, wA0, acc[0], 0, 0, 0);
    acc[1] = __builtin_amdgcn_mfma_f32_16x16x32_bf16(aA, wA1, acc[1], 0, 0, 0);
    acc[2] = __builtin_amdgcn_mfma_f32_16x16x32_bf16(aA, wA2, acc[2], 0, 0, 0);
    acc[3] = __builtin_amdgcn_mfma_f32_16x16x32_bf16(aA, wA3, acc[3], 0, 0, 0);
    acc[0] = __builtin_amdgcn_mfma_f32_16x16x32_bf16(aB, wB0, acc[0], 0, 0, 0);
    acc[1] = __builtin_amdgcn_mfma_f32_16x16x32_bf16(aB, wB1, acc[1], 0, 0, 0);
    acc[2] = __builtin_amdgcn_mfma_f32_16x16x32_bf16(aB, wB2, acc[2], 0, 0, 0);
    acc[3] = __builtin_amdgcn_mfma_f32_16x16x32_bf16(aB, wB3, acc[3], 0, 0, 0);

    aA = aC; aB = aD;
    wA0 = wC0; wA1 = wC1; wA2 = wC2; wA3 = wC3;
    wB0 = wD0; wB1 = wD1; wB2 = wD2; wB3 = wD3;
  }

#pragma unroll
  for (int t = 0; t < 4; ++t) {
    int n = n0 + t * 16 + lo;
#pragma unroll
    for (int j = 0; j < 4; ++j) {
      int m = m0 + g * 4 + j;
      if (n < HEADD) {
        qm[(size_t)m * HEADD + n] = f2bs(acc[t][j] * 0.125f);   // fold 1/sqrt(64)
      } else if (n < 2 * HEADD) {
        kb[(size_t)m * HEADD + (n - HEADD)] = f2bs(acc[t][j]);
      } else {
        int h = n - 2 * HEADD;
        int bb = m >> 12, s = m & (S_LEN - 1);
        vt[((size_t)bb * HEADD + h) * S_LEN + s] = f2bs(acc[t][j]);
      }
    }
  }
}

// ---- Kernel 2b: fp32-source fallback proj (R10's proven version) for small ws
__global__ __launch_bounds__(256, 3) void proj_f32_kernel(const float* __restrict__ x,
                                                          const short* __restrict__ wc,
                                                          short* __restrict__ qm,
                                                          short* __restrict__ kb,
                                                          short* __restrict__ vt) {
  const int w = threadIdx.x >> 6;
  const int lane = threadIdx.x & 63;
  const int lo = lane & 15, g = lane >> 4;
  const int m0 = blockIdx.x * 32;
  const int n0 = blockIdx.y * 192 + w * 48;

  const float* xrow0 = x + (size_t)(m0 + lo) * DMODEL;
  const float* xrow1 = x + (size_t)(m0 + 16 + lo) * DMODEL;
  const short* wrow = wc + (size_t)(n0 + lo) * DMODEL;

  floatx4 acc[3][2];
#pragma unroll
  for (int t = 0; t < 3; ++t)
#pragma unroll
    for (int mm = 0; mm < 2; ++mm) acc[t][mm] = floatx4{0.f, 0.f, 0.f, 0.f};

  float4 a00 = *(const float4*)(xrow0 + g * 8);
  float4 a01 = *(const float4*)(xrow0 + g * 8 + 4);
  float4 a10 = *(const float4*)(xrow1 + g * 8);
  float4 a11 = *(const float4*)(xrow1 + g * 8 + 4);
  short8 wf[3];
#pragma unroll
  for (int t = 0; t < 3; ++t) wf[t] = *(const short8*)(wrow + t * 16 * DMODEL + g * 8);

#pragma unroll 1
  for (int k = 0; k < DMODEL; k += 32) {
    const int kn = (k + 32 < DMODEL) ? k + 32 : 0;
    float4 b00 = *(const float4*)(xrow0 + kn + g * 8);
    float4 b01 = *(const float4*)(xrow0 + kn + g * 8 + 4);
    float4 b10 = *(const float4*)(xrow1 + kn + g * 8);
    float4 b11 = *(const float4*)(xrow1 + kn + g * 8 + 4);
    short8 wn[3];
#pragma unroll
    for (int t = 0; t < 3; ++t) wn[t] = *(const short8*)(wrow + t * 16 * DMODEL + kn + g * 8);

    short8 af0, af1;
    af0[0] = f2bs(a00.x); af0[1] = f2bs(a00.y); af0[2] = f2bs(a00.z); af0[3] = f2bs(a00.w);
    af0[4] = f2bs(a01.x); af0[5] = f2bs(a01.y); af0[6] = f2bs(a01.z); af0[7] = f2bs(a01.w);
    af1[0] = f2bs(a10.x); af1[1] = f2bs(a10.y); af1[2] = f2bs(a10.z); af1[3] = f2bs(a10.w);
    af1[4] = f2bs(a11.x); af1[5] = f2bs(a11.y); af1[6] = f2bs(a11.z); af1[7] = f2bs(a11.w);
#pragma unroll
    for (int t = 0; t < 3; ++t) {
      acc[t][0] = __builtin_amdgcn_mfma_f32_16x16x32_bf16(af0, wf[t], acc[t][0], 0, 0, 0);
      acc[t][1] = __builtin_amdgcn_mfma_f32_16x16x32_bf16(af1, wf[t], acc[t][1], 0, 0, 0);
    }
    a00 = b00; a01 = b01; a10 = b10; a11 = b11;
    wf[0] = wn[0]; wf[1] = wn[1]; wf[2] = wn[2];
  }

#pragma unroll
  for (int t = 0; t < 3; ++t) {
    int n = n0 + t * 16 + lo;
#pragma unroll
    for (int mm = 0; mm < 2; ++mm)
#pragma unroll
      for (int j = 0; j < 4; ++j) {
        int m = m0 + mm * 16 + g * 4 + j;
        if (n < HEADD) {
          qm[(size_t)m * HEADD + n] = f2bs(acc[t][mm][j] * 0.125f);
        } else if (n < 2 * HEADD) {
          kb[(size_t)m * HEADD + (n - HEADD)] = f2bs(acc[t][mm][j]);
        } else {
          int h = n - 2 * HEADD;
          int bb = m >> 12, s = m & (S_LEN - 1);
          vt[((size_t)bb * HEADD + h) * S_LEN + s] = f2bs(acc[t][mm][j]);
        }
      }
  }
}

// ---- Kernel 3: LDS-staged flash attention -> fp32 atomic partial accumulators
// (unchanged from R10)
__global__ __launch_bounds__(512, 4) void attn_kernel(const short* __restrict__ qm,
                                                      const short* __restrict__ kb,
                                                      const short* __restrict__ vt,
                                                      float* __restrict__ ao,
                                                      float* __restrict__ al) {
  const int tid = threadIdx.x;
  const int w = tid >> 6;
  const int lane = tid & 63;
  const int lo = lane & 15, g = lane >> 4;
  const int qs = w >> 1;
  const int s = w & 1;
  const int id = blockIdx.x;
  const int qblk = id >> 2;
  const int ksp = id & 3;
  const int b = qblk >> 6;
  const int kv_base = ksp * 1024;

  __shared__ short kt[2][32][136];
  __shared__ short vl[2][128][40];

  const int kr = tid >> 4, kc = tid & 15;
  const int vh = tid >> 2, vc = tid & 3;
  const short* kS = kb + (size_t)b * S_LEN * HEADD;
  const short* vS = vt + (size_t)b * HEADD * S_LEN;

  const int rowq = qblk * 64 + qs * 16;
  const short* qrow = qm + (size_t)(rowq + lo) * HEADD + s * 64;
  const short8 qf0 = *(const short8*)(qrow + g * 8);
  const short8 qf1 = *(const short8*)(qrow + 32 + g * 8);

  floatx4 acc[8];
#pragma unroll
  for (int n = 0; n < 8; ++n) acc[n] = floatx4{0.f, 0.f, 0.f, 0.f};
  float lx = 0.f;

  const int gA = (g & 1) * 2;
  const int idx0 = lo + 16 * gA, idx1 = idx0 + 16;
  const bool hi = (g >= 2);

  {
    int4 k0 = *(const int4*)(kS + (size_t)(kv_base + kr) * HEADD + kc * 8);
    int4 v0 = *(const int4*)(vS + (size_t)vh * S_LEN + kv_base + vc * 8);
    *(int4*)(&kt[0][kr][kc * 8]) = k0;
    *(int4*)(&vl[0][vh][vc * 8]) = v0;
  }
  __syncthreads();

  int cur = 0;
#pragma unroll 1
  for (int it = 0; it < 32; ++it) {
    int4 knx, vnx;
    if (it + 1 < 32) {
      const int kvn = kv_base + (it + 1) * 32;
      knx = *(const int4*)(kS + (size_t)(kvn + kr) * HEADD + kc * 8);
      vnx = *(const int4*)(vS + (size_t)vh * S_LEN + kvn + vc * 8);
    }

    floatx4 z = floatx4{0.f, 0.f, 0.f, 0.f};
    const short* kp0 = &kt[cur][lo][s * 64 + g * 8];
    short8 a00 = *(const short8*)(kp0);
    short8 a01 = *(const short8*)(kp0 + 32);
    floatx4 u0 = __builtin_amdgcn_mfma_f32_16x16x32_bf16(a00, qf0, z, 0, 0, 0);
    floatx4 T0 = __builtin_amdgcn_mfma_f32_16x16x32_bf16(a01, qf1, u0, 0, 0, 0);
    const short* kp1 = &kt[cur][16 + lo][s * 64 + g * 8];
    short8 a10 = *(const short8*)(kp1);
    short8 a11 = *(const short8*)(kp1 + 32);
    floatx4 u1 = __builtin_amdgcn_mfma_f32_16x16x32_bf16(a10, qf0, z, 0, 0, 0);
    floatx4 T1 = __builtin_amdgcn_mfma_f32_16x16x32_bf16(a11, qf1, u1, 0, 0, 0);

    float p0 = __expf(T0[0]), p1 = __expf(T0[1]), p2 = __expf(T0[2]), p3 = __expf(T0[3]);
    float p4 = __expf(T1[0]), p5 = __expf(T1[1]), p6 = __expf(T1[2]), p7 = __expf(T1[3]);

    float lp = ((p0 + p1) + (p2 + p3)) + ((p4 + p5) + (p6 + p7));
    lp += __shfl_xor(lp, 16);
    lp += __shfl_xor(lp, 32);
    lx += lp;

    int c00 = pkbf(p0, p1), c01 = pkbf(p2, p3);
    int c10 = pkbf(p4, p5), c11 = pkbf(p6, p7);
    int t0a = __shfl(c00, idx0), t0b = __shfl(c01, idx0);
    int t0c = __shfl(c00, idx1), t0d = __shfl(c01, idx1);
    int t1a = __shfl(c10, idx0), t1b = __shfl(c11, idx0);
    int t1c = __shfl(c10, idx1), t1d = __shfl(c11, idx1);
    int w0 = hi ? t1a : t0a, w1 = hi ? t1b : t0b;
    int w2 = hi ? t1c : t0c, w3 = hi ? t1d : t0d;
    short8 pa;
    { int4 tmp = {w0, w1, w2, w3}; __builtin_memcpy(&pa, &tmp, 16); }

#pragma unroll
    for (int n = 0; n < 8; ++n) {
      short8 vf = *(const short8*)(&vl[cur][n * 16 + lo][g * 8]);
      acc[n] = __builtin_amdgcn_mfma_f32_16x16x32_bf16(pa, vf, acc[n], 0, 0, 0);
    }

    if (it + 1 < 32) {
      *(int4*)(&kt[cur ^ 1][kr][kc * 8]) = knx;
      *(int4*)(&vl[cur ^ 1][vh][vc * 8]) = vnx;
    }
    __syncthreads();
    cur ^= 1;
  }

  float* aw = ao + ((size_t)s * 8192 + rowq) * 128;
#pragma unroll
  for (int n = 0; n < 8; ++n)
#pragma unroll
    for (int j = 0; j < 4; ++j)
      atomicAdd(&aw[(size_t)(g * 4 + j) * 128 + n * 16 + lo], acc[n][j]);
  if (g == 0)
    atomicAdd(&al[(size_t)s * 8192 + rowq + lo], lx);
}

// ---- Kernel 4: normalize + diff combine + RMSNorm -> out (unchanged)
__global__ __launch_bounds__(256) void merge_kernel(const float* __restrict__ ao,
                                                    const float* __restrict__ al,
                                                    const float* __restrict__ lq1,
                                                    const float* __restrict__ lq2,
                                                    const float* __restrict__ lk1,
                                                    const float* __restrict__ lk2,
                                                    const float* __restrict__ rmsw,
                                                    float* __restrict__ out) {
  const int tid = threadIdx.x;
  const int gr = blockIdx.x * 8 + (tid >> 5);
  const int c0 = (tid & 31) * 4;

  float a1s = 0.f, a2s = 0.f;
  for (int i = 0; i < 64; ++i) {
    a1s = fmaf(lq1[i], lk1[i], a1s);
    a2s = fmaf(lq2[i], lk2[i], a2s);
  }
  const float lam = __expf(a1s) - __expf(a2s) + 0.7836057665316245f;

  float4 o1 = *(const float4*)(ao + ((size_t)0 * 8192 + gr) * 128 + c0);
  float4 o2 = *(const float4*)(ao + ((size_t)1 * 8192 + gr) * 128 + c0);
  const float iL1 = 1.f / al[gr];
  const float iL2 = 1.f / al[8192 + gr];

  float v[4];
  v[0] = o1.x * iL1 - lam * (o2.x * iL2);
  v[1] = o1.y * iL1 - lam * (o2.y * iL2);
  v[2] = o1.z * iL1 - lam * (o2.z * iL2);
  v[3] = o1.w * iL1 - lam * (o2.w * iL2);
  float ssq = v[0] * v[0] + v[1] * v[1] + v[2] * v[2] + v[3] * v[3];
#pragma unroll
  for (int d = 1; d < 32; d <<= 1) ssq += __shfl_xor(ssq, d);
  const float rr = rsqrtf(ssq * (1.f / 128.f) + 1.1920928955078125e-07f);

  float4 wv4 = *(const float4*)(rmsw + c0);
  float4 r4;
  r4.x = 0.21639423346837554f * v[0] * rr * wv4.x;
  r4.y = 0.21639423346837554f * v[1] * rr * wv4.y;
  r4.z = 0.21639423346837554f * v[2] * rr * wv4.z;
  r4.w = 0.21639423346837554f * v[3] * rr * wv4.w;
  *(float4*)(out + (size_t)gr * 128 + c0) = r4;
}

extern "C" void kernel_launch(void* const* d_in, const int* in_sizes, int n_in,
                              void* d_out, int out_size, void* d_ws, size_t ws_size,
                              hipStream_t stream) {
  const float* x   = (const float*)d_in[0];
  const float* wq  = (const float*)d_in[1];
  const float* wk  = (const float*)d_in[2];
  const float* wv  = (const float*)d_in[3];
  const float* lq1 = (const float*)d_in[4];
  const float* lq2 = (const float*)d_in[5];
  const float* lk1 = (const float*)d_in[6];
  const float* lk2 = (const float*)d_in[7];
  const float* rw  = (const float*)d_in[8];
  float* out = (float*)d_out;

  char* ws = (char*)d_ws;
  short* qm = (short*)(ws);                    // 2 MB (q pre-scaled 0.125)
  short* kb = (short*)(ws + (2u << 20));       // 2 MB
  short* vt = (short*)(ws + (4u << 20));       // 2 MB (V transposed [b][h][s])
  short* wc = (short*)(ws + (6u << 20));       // 1.5 MB
  float* ao = (float*)(ws + (8u << 20));       // 8 MB [2][8192][128] (aliases xb head)
  float* al = (float*)(ws + (16u << 20));      // 64 KB [2][8192]   (aliases xb)
  short* xb = (short*)(ws + (8u << 20));       // 32 MB bf16 X (dead after proj)

  const bool big = ws_size >= (41ull << 20);

  convw_kernel<<<768, 256, 0, stream>>>(wq, wk, wv, wc);
  if (big) {
    convx_kernel<<<8192, 256, 0, stream>>>(x, xb);
    proj_bf16_kernel<<<768, 256, 0, stream>>>(xb, wc, qm, kb, vt);
  } else {
    proj_f32_kernel<<<dim3(256, 2), 256, 0, stream>>>(x, wc, qm, kb, vt);
  }
  // zero atomic accumulators AFTER proj (ao/al alias the xb region)
  hipMemsetAsync(ws + (8u << 20), 0, (8u << 20) + 65536u, stream);
  attn_kernel<<<512, 512, 0, stream>>>(qm, kb, vt, ao, al);
  merge_kernel<<<1024, 256, 0, stream>>>(ao, al, lq1, lq2, lk1, lk2, rw, out);
}

// Round 13
// 148.473 us; speedup vs baseline: 1.5572x; 1.4591x over previous
//
#include <hip/hip_runtime.h>
#include <hip/hip_bf16.h>
#include <math.h>

#define S_LEN 4096
#define DMODEL 2048
#define HEADD 128

typedef __attribute__((ext_vector_type(8))) short short8;
typedef __attribute__((ext_vector_type(4))) float floatx4;

__device__ __forceinline__ short f2bs(float f) {
  __hip_bfloat16 h = __float2bfloat16(f);
  short s; __builtin_memcpy(&s, &h, 2); return s;
}
__device__ __forceinline__ int pkbf(float a, float b) {  // (lo=a, hi=b) bf16 pair
  return (int)(((unsigned)(unsigned short)f2bs(b) << 16) |
               (unsigned)(unsigned short)f2bs(a));
}

// ---- Kernel 1: convert Wq,Wk,Wv (fp32 [128][2048] each) -> wc bf16 [384][2048]
__global__ __launch_bounds__(256) void convw_kernel(const float* __restrict__ wq,
                                                    const float* __restrict__ wk,
                                                    const float* __restrict__ wv,
                                                    short* __restrict__ wc) {
  const int per = 128 * 2048;
  int e = (blockIdx.x * blockDim.x + threadIdx.x) * 4;
  const float* src = (e < per) ? wq : (e < 2 * per) ? wk : wv;
  int off = e & (per - 1);
  float4 v = *(const float4*)(src + off);
  short4 r;
  r.x = f2bs(v.x); r.y = f2bs(v.y); r.z = f2bs(v.z); r.w = f2bs(v.w);
  *(short4*)(wc + e) = r;
}

// ---- Kernel 2: projection GEMM via LDS-staged dbuf (attn's proven structure).
// grid 1024 = (256 m-blocks of 32) x (2 n-halves of 192) x (2 k-halves of 1024).
// 256 thr = 4 waves = (m-sub 0/1) x (n-sub 0/1); wave = 16 rows x 96 cols,
// acc[6] only (~75 regs). Per 32-k step: X 32x32 fp32->bf16 + W 192x32 bf16
// reg-staged into padded LDS, 1 barrier/step. 35KB LDS -> 4 blocks/CU =
// 16 waves/CU. fp32 atomicAdd k-half partials into qa[8192][384].
__global__ __launch_bounds__(256, 4) void proj_kernel(const float* __restrict__ x,
                                                      const short* __restrict__ wc,
                                                      float* __restrict__ qa) {
  const int tid = threadIdx.x;
  const int w = tid >> 6;
  const int lane = tid & 63;
  const int lo = lane & 15, g = lane >> 4;
  const int id = blockIdx.x;
  const int mb = id & 255, nb = (id >> 8) & 1, kh = id >> 9;
  const int m0 = mb * 32;
  const int n0 = nb * 192;
  const int k0 = kh * 1024;

  __shared__ short xt[2][32][40];    // X tile (bf16, pad->2-way reads)
  __shared__ short wt[2][192][40];   // W tile

  // staging assignments
  const int xr = tid >> 3, xk = (tid & 7) * 4;     // X: row, 4-float chunk
  const int wr = tid >> 2, wq4 = (tid & 3) * 8;    // W: row(+c*64), 16B chunk
  const float* xsrc = x + (size_t)(m0 + xr) * DMODEL + k0 + xk;
  const short* wsrc = wc + (size_t)(n0 + wr) * DMODEL + k0 + wq4;

  const int mrow = (w >> 1) * 16;
  const int ncol = (w & 1) * 96;

  floatx4 acc[6];
#pragma unroll
  for (int t = 0; t < 6; ++t) acc[t] = floatx4{0.f, 0.f, 0.f, 0.f};

  // prologue: stage step 0
  {
    float4 xv = *(const float4*)(xsrc);
    short4 xs;
    xs.x = f2bs(xv.x); xs.y = f2bs(xv.y); xs.z = f2bs(xv.z); xs.w = f2bs(xv.w);
    *(short4*)(&xt[0][xr][xk]) = xs;
#pragma unroll
    for (int c = 0; c < 3; ++c) {
      int4 wv = *(const int4*)(wsrc + (size_t)c * 64 * DMODEL);
      *(int4*)(&wt[0][c * 64 + wr][wq4]) = wv;
    }
  }
  __syncthreads();

  int cur = 0;
#pragma unroll 1
  for (int it = 0; it < 32; ++it) {
    float4 xn;
    int4 wn0, wn1, wn2;
    if (it + 1 < 32) {                       // issue next-step loads early
      const int kn = (it + 1) * 32;
      xn = *(const float4*)(xsrc + kn);
      wn0 = *(const int4*)(wsrc + kn);
      wn1 = *(const int4*)(wsrc + (size_t)64 * DMODEL + kn);
      wn2 = *(const int4*)(wsrc + (size_t)128 * DMODEL + kn);
    }

    // compute from LDS[cur]: 1 A-frag + 6 B-frags, 6 MFMAs
    short8 af = *(const short8*)(&xt[cur][mrow + lo][g * 8]);
#pragma unroll
    for (int t = 0; t < 6; ++t) {
      short8 bf = *(const short8*)(&wt[cur][ncol + t * 16 + lo][g * 8]);
      acc[t] = __builtin_amdgcn_mfma_f32_16x16x32_bf16(af, bf, acc[t], 0, 0, 0);
    }

    if (it + 1 < 32) {                       // write next tile (forces loads early)
      short4 xs;
      xs.x = f2bs(xn.x); xs.y = f2bs(xn.y); xs.z = f2bs(xn.z); xs.w = f2bs(xn.w);
      *(short4*)(&xt[cur ^ 1][xr][xk]) = xs;
      *(int4*)(&wt[cur ^ 1][0 * 64 + wr][wq4]) = wn0;
      *(int4*)(&wt[cur ^ 1][1 * 64 + wr][wq4]) = wn1;
      *(int4*)(&wt[cur ^ 1][2 * 64 + wr][wq4]) = wn2;
    }
    __syncthreads();
    cur ^= 1;
  }

  // epilogue: fp32 atomic k-half merge
#pragma unroll
  for (int t = 0; t < 6; ++t) {
    int n = n0 + ncol + t * 16 + lo;
#pragma unroll
    for (int j = 0; j < 4; ++j) {
      int m = m0 + mrow + g * 4 + j;
      atomicAdd(&qa[(size_t)m * 384 + n], acc[t][j]);
    }
  }
}

// ---- Kernel 2b: qa[:, 0:256] -> qm (scaled 0.125), kb
__global__ __launch_bounds__(256) void conv_qk_kernel(const float* __restrict__ qa,
                                                      short* __restrict__ qm,
                                                      short* __restrict__ kb) {
  int e = (blockIdx.x * 256 + threadIdx.x) * 4;   // over [8192][256]
  int m = e >> 8, c = e & 255;
  float4 v = *(const float4*)(qa + (size_t)m * 384 + c);
  short4 r;
  if (c < 128) {
    r.x = f2bs(v.x * 0.125f); r.y = f2bs(v.y * 0.125f);
    r.z = f2bs(v.z * 0.125f); r.w = f2bs(v.w * 0.125f);
    *(short4*)(qm + (size_t)m * 128 + c) = r;
  } else {
    r.x = f2bs(v.x); r.y = f2bs(v.y); r.z = f2bs(v.z); r.w = f2bs(v.w);
    *(short4*)(kb + (size_t)m * 128 + (c - 128)) = r;
  }
}

// ---- Kernel 2c: qa[:, 256:384] -> vt[b][h][s] (transposed; coalesced writes)
__global__ __launch_bounds__(256) void conv_v_kernel(const float* __restrict__ qa,
                                                     short* __restrict__ vt) {
  int e = blockIdx.x * 256 + threadIdx.x;   // over [2][128][1024] s-quads
  int s4 = e & 1023, h = (e >> 10) & 127, bb = e >> 17;
  int s = s4 * 4;
  const float* src = qa + ((size_t)bb * 4096 + s) * 384 + 256 + h;
  short4 r;
  r.x = f2bs(src[0]);
  r.y = f2bs(src[384]);
  r.z = f2bs(src[768]);
  r.w = f2bs(src[1152]);
  *(short4*)(vt + ((size_t)bb * 128 + h) * 4096 + s) = r;
}

// ---- Kernel 3: LDS-staged flash attention -> fp32 atomic partial accumulators
// (unchanged from R10/R12)
__global__ __launch_bounds__(512, 4) void attn_kernel(const short* __restrict__ qm,
                                                      const short* __restrict__ kb,
                                                      const short* __restrict__ vt,
                                                      float* __restrict__ ao,
                                                      float* __restrict__ al) {
  const int tid = threadIdx.x;
  const int w = tid >> 6;
  const int lane = tid & 63;
  const int lo = lane & 15, g = lane >> 4;
  const int qs = w >> 1;
  const int s = w & 1;
  const int id = blockIdx.x;
  const int qblk = id >> 2;
  const int ksp = id & 3;
  const int b = qblk >> 6;
  const int kv_base = ksp * 1024;

  __shared__ short kt[2][32][136];
  __shared__ short vl[2][128][40];

  const int kr = tid >> 4, kc = tid & 15;
  const int vh = tid >> 2, vc = tid & 3;
  const short* kS = kb + (size_t)b * S_LEN * HEADD;
  const short* vS = vt + (size_t)b * HEADD * S_LEN;

  const int rowq = qblk * 64 + qs * 16;
  const short* qrow = qm + (size_t)(rowq + lo) * HEADD + s * 64;
  const short8 qf0 = *(const short8*)(qrow + g * 8);
  const short8 qf1 = *(const short8*)(qrow + 32 + g * 8);

  floatx4 acc[8];
#pragma unroll
  for (int n = 0; n < 8; ++n) acc[n] = floatx4{0.f, 0.f, 0.f, 0.f};
  float lx = 0.f;

  const int gA = (g & 1) * 2;
  const int idx0 = lo + 16 * gA, idx1 = idx0 + 16;
  const bool hi = (g >= 2);

  {
    int4 k0 = *(const int4*)(kS + (size_t)(kv_base + kr) * HEADD + kc * 8);
    int4 v0 = *(const int4*)(vS + (size_t)vh * S_LEN + kv_base + vc * 8);
    *(int4*)(&kt[0][kr][kc * 8]) = k0;
    *(int4*)(&vl[0][vh][vc * 8]) = v0;
  }
  __syncthreads();

  int cur = 0;
#pragma unroll 1
  for (int it = 0; it < 32; ++it) {
    int4 knx, vnx;
    if (it + 1 < 32) {
      const int kvn = kv_base + (it + 1) * 32;
      knx = *(const int4*)(kS + (size_t)(kvn + kr) * HEADD + kc * 8);
      vnx = *(const int4*)(vS + (size_t)vh * S_LEN + kvn + vc * 8);
    }

    floatx4 z = floatx4{0.f, 0.f, 0.f, 0.f};
    const short* kp0 = &kt[cur][lo][s * 64 + g * 8];
    short8 a00 = *(const short8*)(kp0);
    short8 a01 = *(const short8*)(kp0 + 32);
    floatx4 u0 = __builtin_amdgcn_mfma_f32_16x16x32_bf16(a00, qf0, z, 0, 0, 0);
    floatx4 T0 = __builtin_amdgcn_mfma_f32_16x16x32_bf16(a01, qf1, u0, 0, 0, 0);
    const short* kp1 = &kt[cur][16 + lo][s * 64 + g * 8];
    short8 a10 = *(const short8*)(kp1);
    short8 a11 = *(const short8*)(kp1 + 32);
    floatx4 u1 = __builtin_amdgcn_mfma_f32_16x16x32_bf16(a10, qf0, z, 0, 0, 0);
    floatx4 T1 = __builtin_amdgcn_mfma_f32_16x16x32_bf16(a11, qf1, u1, 0, 0, 0);

    float p0 = __expf(T0[0]), p1 = __expf(T0[1]), p2 = __expf(T0[2]), p3 = __expf(T0[3]);
    float p4 = __expf(T1[0]), p5 = __expf(T1[1]), p6 = __expf(T1[2]), p7 = __expf(T1[3]);

    float lp = ((p0 + p1) + (p2 + p3)) + ((p4 + p5) + (p6 + p7));
    lp += __shfl_xor(lp, 16);
    lp += __shfl_xor(lp, 32);
    lx += lp;

    int c00 = pkbf(p0, p1), c01 = pkbf(p2, p3);
    int c10 = pkbf(p4, p5), c11 = pkbf(p6, p7);
    int t0a = __shfl(c00, idx0), t0b = __shfl(c01, idx0);
    int t0c = __shfl(c00, idx1), t0d = __shfl(c01, idx1);
    int t1a = __shfl(c10, idx0), t1b = __shfl(c11, idx0);
    int t1c = __shfl(c10, idx1), t1d = __shfl(c11, idx1);
    int w0 = hi ? t1a : t0a, w1 = hi ? t1b : t0b;
    int w2 = hi ? t1c : t0c, w3 = hi ? t1d : t0d;
    short8 pa;
    { int4 tmp = {w0, w1, w2, w3}; __builtin_memcpy(&pa, &tmp, 16); }

#pragma unroll
    for (int n = 0; n < 8; ++n) {
      short8 vf = *(const short8*)(&vl[cur][n * 16 + lo][g * 8]);
      acc[n] = __builtin_amdgcn_mfma_f32_16x16x32_bf16(pa, vf, acc[n], 0, 0, 0);
    }

    if (it + 1 < 32) {
      *(int4*)(&kt[cur ^ 1][kr][kc * 8]) = knx;
      *(int4*)(&vl[cur ^ 1][vh][vc * 8]) = vnx;
    }
    __syncthreads();
    cur ^= 1;
  }

  float* aw = ao + ((size_t)s * 8192 + rowq) * 128;
#pragma unroll
  for (int n = 0; n < 8; ++n)
#pragma unroll
    for (int j = 0; j < 4; ++j)
      atomicAdd(&aw[(size_t)(g * 4 + j) * 128 + n * 16 + lo], acc[n][j]);
  if (g == 0)
    atomicAdd(&al[(size_t)s * 8192 + rowq + lo], lx);
}

// ---- Kernel 4: normalize + diff combine + RMSNorm -> out (unchanged)
__global__ __launch_bounds__(256) void merge_kernel(const float* __restrict__ ao,
                                                    const float* __restrict__ al,
                                                    const float* __restrict__ lq1,
                                                    const float* __restrict__ lq2,
                                                    const float* __restrict__ lk1,
                                                    const float* __restrict__ lk2,
                                                    const float* __restrict__ rmsw,
                                                    float* __restrict__ out) {
  const int tid = threadIdx.x;
  const int gr = blockIdx.x * 8 + (tid >> 5);
  const int c0 = (tid & 31) * 4;

  float a1s = 0.f, a2s = 0.f;
  for (int i = 0; i < 64; ++i) {
    a1s = fmaf(lq1[i], lk1[i], a1s);
    a2s = fmaf(lq2[i], lk2[i], a2s);
  }
  const float lam = __expf(a1s) - __expf(a2s) + 0.7836057665316245f;

  float4 o1 = *(const float4*)(ao + ((size_t)0 * 8192 + gr) * 128 + c0);
  float4 o2 = *(const float4*)(ao + ((size_t)1 * 8192 + gr) * 128 + c0);
  const float iL1 = 1.f / al[gr];
  const float iL2 = 1.f / al[8192 + gr];

  float v[4];
  v[0] = o1.x * iL1 - lam * (o2.x * iL2);
  v[1] = o1.y * iL1 - lam * (o2.y * iL2);
  v[2] = o1.z * iL1 - lam * (o2.z * iL2);
  v[3] = o1.w * iL1 - lam * (o2.w * iL2);
  float ssq = v[0] * v[0] + v[1] * v[1] + v[2] * v[2] + v[3] * v[3];
#pragma unroll
  for (int d = 1; d < 32; d <<= 1) ssq += __shfl_xor(ssq, d);
  const float rr = rsqrtf(ssq * (1.f / 128.f) + 1.1920928955078125e-07f);

  float4 wv4 = *(const float4*)(rmsw + c0);
  float4 r4;
  r4.x = 0.21639423346837554f * v[0] * rr * wv4.x;
  r4.y = 0.21639423346837554f * v[1] * rr * wv4.y;
  r4.z = 0.21639423346837554f * v[2] * rr * wv4.z;
  r4.w = 0.21639423346837554f * v[3] * rr * wv4.w;
  *(float4*)(out + (size_t)gr * 128 + c0) = r4;
}

extern "C" void kernel_launch(void* const* d_in, const int* in_sizes, int n_in,
                              void* d_out, int out_size, void* d_ws, size_t ws_size,
                              hipStream_t stream) {
  const float* x   = (const float*)d_in[0];
  const float* wq  = (const float*)d_in[1];
  const float* wk  = (const float*)d_in[2];
  const float* wv  = (const float*)d_in[3];
  const float* lq1 = (const float*)d_in[4];
  const float* lq2 = (const float*)d_in[5];
  const float* lk1 = (const float*)d_in[6];
  const float* lk2 = (const float*)d_in[7];
  const float* rw  = (const float*)d_in[8];
  float* out = (float*)d_out;

  char* ws = (char*)d_ws;
  short* qm = (short*)(ws);                    // 2 MB (q pre-scaled 0.125)
  short* kb = (short*)(ws + (2u << 20));       // 2 MB
  short* vt = (short*)(ws + (4u << 20));       // 2 MB (V transposed [b][h][s])
  short* wc = (short*)(ws + (6u << 20));       // 1.5 MB
  float* ao = (float*)(ws + (8u << 20));       // 8 MB [2][8192][128]
  float* al = (float*)(ws + (16u << 20));      // 64 KB [2][8192]
  float* qa = (float*)(ws + (16u << 20) + 65536u);  // 12.6 MB [8192][384] fp32

  // zero ao+al+qa in one shot (all contiguous from 8MB)
  hipMemsetAsync(ws + (8u << 20), 0, 8388608u + 65536u + 12582912u, stream);

  convw_kernel<<<768, 256, 0, stream>>>(wq, wk, wv, wc);
  proj_kernel<<<1024, 256, 0, stream>>>(x, wc, qa);
  conv_qk_kernel<<<2048, 256, 0, stream>>>(qa, qm, kb);
  conv_v_kernel<<<1024, 256, 0, stream>>>(qa, vt);
  attn_kernel<<<512, 512, 0, stream>>>(qm, kb, vt, ao, al);
  merge_kernel<<<1024, 256, 0, stream>>>(ao, al, lq1, lq2, lk1, lk2, rw, out);
}

// Round 14
// 143.022 us; speedup vs baseline: 1.6166x; 1.0381x over previous
//
#include <hip/hip_runtime.h>
#include <hip/hip_bf16.h>
#include <math.h>

#define S_LEN 4096
#define DMODEL 2048
#define HEADD 128

typedef __attribute__((ext_vector_type(8))) short short8;
typedef __attribute__((ext_vector_type(4))) float floatx4;

__device__ __forceinline__ short f2bs(float f) {
  __hip_bfloat16 h = __float2bfloat16(f);
  short s; __builtin_memcpy(&s, &h, 2); return s;
}
__device__ __forceinline__ int pkbf(float a, float b) {  // (lo=a, hi=b) bf16 pair
  return (int)(((unsigned)(unsigned short)f2bs(b) << 16) |
               (unsigned)(unsigned short)f2bs(a));
}

// ---- Kernel 1: convert Wq,Wk,Wv (fp32 [128][2048] each) -> wc bf16 [384][2048]
__global__ __launch_bounds__(256) void convw_kernel(const float* __restrict__ wq,
                                                    const float* __restrict__ wk,
                                                    const float* __restrict__ wv,
                                                    short* __restrict__ wc) {
  const int per = 128 * 2048;
  int e = (blockIdx.x * blockDim.x + threadIdx.x) * 4;
  const float* src = (e < per) ? wq : (e < 2 * per) ? wk : wv;
  int off = e & (per - 1);
  float4 v = *(const float4*)(src + off);
  short4 r;
  r.x = f2bs(v.x); r.y = f2bs(v.y); r.z = f2bs(v.z); r.w = f2bs(v.w);
  *(short4*)(wc + e) = r;
}

// ---- Kernel 2: projection GEMM via LDS-staged dbuf (unchanged from R13)
__global__ __launch_bounds__(256, 4) void proj_kernel(const float* __restrict__ x,
                                                      const short* __restrict__ wc,
                                                      float* __restrict__ qa) {
  const int tid = threadIdx.x;
  const int w = tid >> 6;
  const int lane = tid & 63;
  const int lo = lane & 15, g = lane >> 4;
  const int id = blockIdx.x;
  const int mb = id & 255, nb = (id >> 8) & 1, kh = id >> 9;
  const int m0 = mb * 32;
  const int n0 = nb * 192;
  const int k0 = kh * 1024;

  __shared__ short xt[2][32][40];
  __shared__ short wt[2][192][40];

  const int xr = tid >> 3, xk = (tid & 7) * 4;
  const int wr = tid >> 2, wq4 = (tid & 3) * 8;
  const float* xsrc = x + (size_t)(m0 + xr) * DMODEL + k0 + xk;
  const short* wsrc = wc + (size_t)(n0 + wr) * DMODEL + k0 + wq4;

  const int mrow = (w >> 1) * 16;
  const int ncol = (w & 1) * 96;

  floatx4 acc[6];
#pragma unroll
  for (int t = 0; t < 6; ++t) acc[t] = floatx4{0.f, 0.f, 0.f, 0.f};

  {
    float4 xv = *(const float4*)(xsrc);
    short4 xs;
    xs.x = f2bs(xv.x); xs.y = f2bs(xv.y); xs.z = f2bs(xv.z); xs.w = f2bs(xv.w);
    *(short4*)(&xt[0][xr][xk]) = xs;
#pragma unroll
    for (int c = 0; c < 3; ++c) {
      int4 wv = *(const int4*)(wsrc + (size_t)c * 64 * DMODEL);
      *(int4*)(&wt[0][c * 64 + wr][wq4]) = wv;
    }
  }
  __syncthreads();

  int cur = 0;
#pragma unroll 1
  for (int it = 0; it < 32; ++it) {
    float4 xn;
    int4 wn0, wn1, wn2;
    if (it + 1 < 32) {
      const int kn = (it + 1) * 32;
      xn = *(const float4*)(xsrc + kn);
      wn0 = *(const int4*)(wsrc + kn);
      wn1 = *(const int4*)(wsrc + (size_t)64 * DMODEL + kn);
      wn2 = *(const int4*)(wsrc + (size_t)128 * DMODEL + kn);
    }

    short8 af = *(const short8*)(&xt[cur][mrow + lo][g * 8]);
#pragma unroll
    for (int t = 0; t < 6; ++t) {
      short8 bf = *(const short8*)(&wt[cur][ncol + t * 16 + lo][g * 8]);
      acc[t] = __builtin_amdgcn_mfma_f32_16x16x32_bf16(af, bf, acc[t], 0, 0, 0);
    }

    if (it + 1 < 32) {
      short4 xs;
      xs.x = f2bs(xn.x); xs.y = f2bs(xn.y); xs.z = f2bs(xn.z); xs.w = f2bs(xn.w);
      *(short4*)(&xt[cur ^ 1][xr][xk]) = xs;
      *(int4*)(&wt[cur ^ 1][0 * 64 + wr][wq4]) = wn0;
      *(int4*)(&wt[cur ^ 1][1 * 64 + wr][wq4]) = wn1;
      *(int4*)(&wt[cur ^ 1][2 * 64 + wr][wq4]) = wn2;
    }
    __syncthreads();
    cur ^= 1;
  }

#pragma unroll
  for (int t = 0; t < 6; ++t) {
    int n = n0 + ncol + t * 16 + lo;
#pragma unroll
    for (int j = 0; j < 4; ++j) {
      int m = m0 + mrow + g * 4 + j;
      atomicAdd(&qa[(size_t)m * 384 + n], acc[t][j]);
    }
  }
}

// ---- Kernel 2b: qa[:, 0:256] -> qm (scaled 0.125), kb
__global__ __launch_bounds__(256) void conv_qk_kernel(const float* __restrict__ qa,
                                                      short* __restrict__ qm,
                                                      short* __restrict__ kb) {
  int e = (blockIdx.x * 256 + threadIdx.x) * 4;
  int m = e >> 8, c = e & 255;
  float4 v = *(const float4*)(qa + (size_t)m * 384 + c);
  short4 r;
  if (c < 128) {
    r.x = f2bs(v.x * 0.125f); r.y = f2bs(v.y * 0.125f);
    r.z = f2bs(v.z * 0.125f); r.w = f2bs(v.w * 0.125f);
    *(short4*)(qm + (size_t)m * 128 + c) = r;
  } else {
    r.x = f2bs(v.x); r.y = f2bs(v.y); r.z = f2bs(v.z); r.w = f2bs(v.w);
    *(short4*)(kb + (size_t)m * 128 + (c - 128)) = r;
  }
}

// ---- Kernel 2c: qa[:, 256:384] -> vt[b][h][s]
__global__ __launch_bounds__(256) void conv_v_kernel(const float* __restrict__ qa,
                                                     short* __restrict__ vt) {
  int e = blockIdx.x * 256 + threadIdx.x;
  int s4 = e & 1023, h = (e >> 10) & 127, bb = e >> 17;
  int s = s4 * 4;
  const float* src = qa + ((size_t)bb * 4096 + s) * 384 + 256 + h;
  short4 r;
  r.x = f2bs(src[0]);
  r.y = f2bs(src[384]);
  r.z = f2bs(src[768]);
  r.w = f2bs(src[1152]);
  *(short4*)(vt + ((size_t)bb * 128 + h) * 4096 + s) = r;
}

// ---- Kernel 3: LDS-staged flash attention, XOR-swizzled tiles, 2 q-subtiles/wave
// 512 blocks = 128 qblk x 4 kv-quarters; 256 thr = 4 waves = (subtile-pair) x
// (stream). Wave owns 32 q-rows: K-frag + V-tile LDS reads serve 2 subtiles
// (halves LDS read traffic vs R13). Tiles linear + XOR chunk swizzle:
//   K [32][128]: chunk' = ck ^ (row&7)  (16B chunks, 16/row)
//   V [128][32]: chunk' = ck ^ (row&3)  (4/row)
// -> all 4 access patterns uniform 8 lanes per 4-bank group (conflict-free).
__global__ __launch_bounds__(256, 3) void attn_kernel(const short* __restrict__ qm,
                                                      const short* __restrict__ kb,
                                                      const short* __restrict__ vt,
                                                      float* __restrict__ ao,
                                                      float* __restrict__ al) {
  const int tid = threadIdx.x;
  const int w = tid >> 6;
  const int lane = tid & 63;
  const int lo = lane & 15, g = lane >> 4;
  const int qsp = w >> 1;           // subtile pair 0/1
  const int s = w & 1;              // attn stream
  const int id = blockIdx.x;
  const int qblk = id >> 2;         // 0..127 global (b = qblk>>6)
  const int ksp = id & 3;
  const int b = qblk >> 6;
  const int kv_base = ksp * 1024;

  __shared__ short kt[2][32 * 128];   // K tile, swizzled
  __shared__ short vl[2][128 * 32];   // V^T tile, swizzled

  // staging: 256 thr x (2 K chunks + 2 V chunks) of 16B
  const int kr0 = tid >> 4, kck = tid & 15;          // K rows kr0, kr0+16
  const int vr0 = tid >> 2, vck = tid & 3;           // V rows vr0, vr0+64
  const short* kS = kb + (size_t)b * S_LEN * HEADD;
  const short* vS = vt + (size_t)b * HEADD * S_LEN;
  const int kld0 = kr0 * 128 + ((kck ^ (kr0 & 7)) * 8);
  const int kld1 = (kr0 + 16) * 128 + ((kck ^ (kr0 & 7)) * 8);
  const int vld0 = vr0 * 32 + ((vck ^ (vr0 & 3)) * 8);
  const int vld1 = (vr0 + 64) * 32 + ((vck ^ (vr0 & 3)) * 8);

  // Q frags for both subtiles (B operand), stream's 64-dim slice
  const int rowqA = qblk * 64 + qsp * 32;
  const int rowqB = rowqA + 16;
  const short* qrowA = qm + (size_t)(rowqA + lo) * HEADD + s * 64;
  const short* qrowB = qm + (size_t)(rowqB + lo) * HEADD + s * 64;
  const short8 qA0 = *(const short8*)(qrowA + g * 8);
  const short8 qA1 = *(const short8*)(qrowA + 32 + g * 8);
  const short8 qB0 = *(const short8*)(qrowB + g * 8);
  const short8 qB1 = *(const short8*)(qrowB + 32 + g * 8);

  floatx4 accA[8], accB[8];
#pragma unroll
  for (int n = 0; n < 8; ++n) {
    accA[n] = floatx4{0.f, 0.f, 0.f, 0.f};
    accB[n] = floatx4{0.f, 0.f, 0.f, 0.f};
  }
  float lxA = 0.f, lxB = 0.f;

  // swizzled K-frag offsets (wave-constant parts)
  const int kc0 = ((s * 8 + g) ^ (lo & 7)) * 8;        // a00/a10 chunk
  const int kc1 = ((s * 8 + 4 + g) ^ (lo & 7)) * 8;    // a01/a11 chunk
  const int kro0 = lo * 128, kro1 = (16 + lo) * 128;
  const int vco = (g ^ (lo & 3)) * 8;                  // V chunk offset

  const int gA = (g & 1) * 2;
  const int idx0 = lo + 16 * gA, idx1 = idx0 + 16;
  const bool hi = (g >= 2);

  // prologue: stage step 0
  {
    int4 ka = *(const int4*)(kS + (size_t)(kv_base + kr0) * HEADD + kck * 8);
    int4 kbx = *(const int4*)(kS + (size_t)(kv_base + kr0 + 16) * HEADD + kck * 8);
    int4 va = *(const int4*)(vS + (size_t)vr0 * S_LEN + kv_base + vck * 8);
    int4 vb = *(const int4*)(vS + (size_t)(vr0 + 64) * S_LEN + kv_base + vck * 8);
    *(int4*)(&kt[0][kld0]) = ka;
    *(int4*)(&kt[0][kld1]) = kbx;
    *(int4*)(&vl[0][vld0]) = va;
    *(int4*)(&vl[0][vld1]) = vb;
  }
  __syncthreads();

  int cur = 0;
#pragma unroll 1
  for (int it = 0; it < 32; ++it) {
    int4 ka, kbx, va, vb;
    if (it + 1 < 32) {                       // issue next-step loads early (T14)
      const int kvn = kv_base + (it + 1) * 32;
      ka  = *(const int4*)(kS + (size_t)(kvn + kr0) * HEADD + kck * 8);
      kbx = *(const int4*)(kS + (size_t)(kvn + kr0 + 16) * HEADD + kck * 8);
      va  = *(const int4*)(vS + (size_t)vr0 * S_LEN + kvn + vck * 8);
      vb  = *(const int4*)(vS + (size_t)(vr0 + 64) * S_LEN + kvn + vck * 8);
    }

    // K-frags (shared by both subtiles)
    const short* kbase = &kt[cur][0];
    short8 a00 = *(const short8*)(kbase + kro0 + kc0);
    short8 a01 = *(const short8*)(kbase + kro0 + kc1);
    short8 a10 = *(const short8*)(kbase + kro1 + kc0);
    short8 a11 = *(const short8*)(kbase + kro1 + kc1);

    floatx4 z = floatx4{0.f, 0.f, 0.f, 0.f};
    floatx4 u;
    u = __builtin_amdgcn_mfma_f32_16x16x32_bf16(a00, qA0, z, 0, 0, 0);
    floatx4 T0A = __builtin_amdgcn_mfma_f32_16x16x32_bf16(a01, qA1, u, 0, 0, 0);
    u = __builtin_amdgcn_mfma_f32_16x16x32_bf16(a10, qA0, z, 0, 0, 0);
    floatx4 T1A = __builtin_amdgcn_mfma_f32_16x16x32_bf16(a11, qA1, u, 0, 0, 0);
    u = __builtin_amdgcn_mfma_f32_16x16x32_bf16(a00, qB0, z, 0, 0, 0);
    floatx4 T0B = __builtin_amdgcn_mfma_f32_16x16x32_bf16(a01, qB1, u, 0, 0, 0);
    u = __builtin_amdgcn_mfma_f32_16x16x32_bf16(a10, qB0, z, 0, 0, 0);
    floatx4 T1B = __builtin_amdgcn_mfma_f32_16x16x32_bf16(a11, qB1, u, 0, 0, 0);

    // subtile A: exp, l, transpose
    short8 paA, paB;
    {
      float p0 = __expf(T0A[0]), p1 = __expf(T0A[1]), p2 = __expf(T0A[2]), p3 = __expf(T0A[3]);
      float p4 = __expf(T1A[0]), p5 = __expf(T1A[1]), p6 = __expf(T1A[2]), p7 = __expf(T1A[3]);
      float lp = ((p0 + p1) + (p2 + p3)) + ((p4 + p5) + (p6 + p7));
      lp += __shfl_xor(lp, 16);
      lp += __shfl_xor(lp, 32);
      lxA += lp;
      int c00 = pkbf(p0, p1), c01 = pkbf(p2, p3);
      int c10 = pkbf(p4, p5), c11 = pkbf(p6, p7);
      int t0a = __shfl(c00, idx0), t0b = __shfl(c01, idx0);
      int t0c = __shfl(c00, idx1), t0d = __shfl(c01, idx1);
      int t1a = __shfl(c10, idx0), t1b = __shfl(c11, idx0);
      int t1c = __shfl(c10, idx1), t1d = __shfl(c11, idx1);
      int w0 = hi ? t1a : t0a, w1 = hi ? t1b : t0b;
      int w2 = hi ? t1c : t0c, w3 = hi ? t1d : t0d;
      int4 tmp = {w0, w1, w2, w3}; __builtin_memcpy(&paA, &tmp, 16);
    }
    // subtile B
    {
      float p0 = __expf(T0B[0]), p1 = __expf(T0B[1]), p2 = __expf(T0B[2]), p3 = __expf(T0B[3]);
      float p4 = __expf(T1B[0]), p5 = __expf(T1B[1]), p6 = __expf(T1B[2]), p7 = __expf(T1B[3]);
      float lp = ((p0 + p1) + (p2 + p3)) + ((p4 + p5) + (p6 + p7));
      lp += __shfl_xor(lp, 16);
      lp += __shfl_xor(lp, 32);
      lxB += lp;
      int c00 = pkbf(p0, p1), c01 = pkbf(p2, p3);
      int c10 = pkbf(p4, p5), c11 = pkbf(p6, p7);
      int t0a = __shfl(c00, idx0), t0b = __shfl(c01, idx0);
      int t0c = __shfl(c00, idx1), t0d = __shfl(c01, idx1);
      int t1a = __shfl(c10, idx0), t1b = __shfl(c11, idx0);
      int t1c = __shfl(c10, idx1), t1d = __shfl(c11, idx1);
      int w0 = hi ? t1a : t0a, w1 = hi ? t1b : t0b;
      int w2 = hi ? t1c : t0c, w3 = hi ? t1d : t0d;
      int4 tmp = {w0, w1, w2, w3}; __builtin_memcpy(&paB, &tmp, 16);
    }

    // PV: V read once serves both subtiles
    const short* vbase = &vl[cur][0];
#pragma unroll
    for (int n = 0; n < 8; ++n) {
      short8 vf = *(const short8*)(vbase + (n * 16 + lo) * 32 + vco);
      accA[n] = __builtin_amdgcn_mfma_f32_16x16x32_bf16(paA, vf, accA[n], 0, 0, 0);
      accB[n] = __builtin_amdgcn_mfma_f32_16x16x32_bf16(paB, vf, accB[n], 0, 0, 0);
    }

    if (it + 1 < 32) {
      *(int4*)(&kt[cur ^ 1][kld0]) = ka;
      *(int4*)(&kt[cur ^ 1][kld1]) = kbx;
      *(int4*)(&vl[cur ^ 1][vld0]) = va;
      *(int4*)(&vl[cur ^ 1][vld1]) = vb;
    }
    __syncthreads();
    cur ^= 1;
  }

  // ---- fp32 atomic merge, both subtiles ----
  float* awA = ao + ((size_t)s * 8192 + rowqA) * 128;
  float* awB = ao + ((size_t)s * 8192 + rowqB) * 128;
#pragma unroll
  for (int n = 0; n < 8; ++n)
#pragma unroll
    for (int j = 0; j < 4; ++j) {
      atomicAdd(&awA[(size_t)(g * 4 + j) * 128 + n * 16 + lo], accA[n][j]);
      atomicAdd(&awB[(size_t)(g * 4 + j) * 128 + n * 16 + lo], accB[n][j]);
    }
  if (g == 0) {
    atomicAdd(&al[(size_t)s * 8192 + rowqA + lo], lxA);
    atomicAdd(&al[(size_t)s * 8192 + rowqB + lo], lxB);
  }
}

// ---- Kernel 4: normalize + diff combine + RMSNorm -> out (unchanged)
__global__ __launch_bounds__(256) void merge_kernel(const float* __restrict__ ao,
                                                    const float* __restrict__ al,
                                                    const float* __restrict__ lq1,
                                                    const float* __restrict__ lq2,
                                                    const float* __restrict__ lk1,
                                                    const float* __restrict__ lk2,
                                                    const float* __restrict__ rmsw,
                                                    float* __restrict__ out) {
  const int tid = threadIdx.x;
  const int gr = blockIdx.x * 8 + (tid >> 5);
  const int c0 = (tid & 31) * 4;

  float a1s = 0.f, a2s = 0.f;
  for (int i = 0; i < 64; ++i) {
    a1s = fmaf(lq1[i], lk1[i], a1s);
    a2s = fmaf(lq2[i], lk2[i], a2s);
  }
  const float lam = __expf(a1s) - __expf(a2s) + 0.7836057665316245f;

  float4 o1 = *(const float4*)(ao + ((size_t)0 * 8192 + gr) * 128 + c0);
  float4 o2 = *(const float4*)(ao + ((size_t)1 * 8192 + gr) * 128 + c0);
  const float iL1 = 1.f / al[gr];
  const float iL2 = 1.f / al[8192 + gr];

  float v[4];
  v[0] = o1.x * iL1 - lam * (o2.x * iL2);
  v[1] = o1.y * iL1 - lam * (o2.y * iL2);
  v[2] = o1.z * iL1 - lam * (o2.z * iL2);
  v[3] = o1.w * iL1 - lam * (o2.w * iL2);
  float ssq = v[0] * v[0] + v[1] * v[1] + v[2] * v[2] + v[3] * v[3];
#pragma unroll
  for (int d = 1; d < 32; d <<= 1) ssq += __shfl_xor(ssq, d);
  const float rr = rsqrtf(ssq * (1.f / 128.f) + 1.1920928955078125e-07f);

  float4 wv4 = *(const float4*)(rmsw + c0);
  float4 r4;
  r4.x = 0.21639423346837554f * v[0] * rr * wv4.x;
  r4.y = 0.21639423346837554f * v[1] * rr * wv4.y;
  r4.z = 0.21639423346837554f * v[2] * rr * wv4.z;
  r4.w = 0.21639423346837554f * v[3] * rr * wv4.w;
  *(float4*)(out + (size_t)gr * 128 + c0) = r4;
}

extern "C" void kernel_launch(void* const* d_in, const int* in_sizes, int n_in,
                              void* d_out, int out_size, void* d_ws, size_t ws_size,
                              hipStream_t stream) {
  const float* x   = (const float*)d_in[0];
  const float* wq  = (const float*)d_in[1];
  const float* wk  = (const float*)d_in[2];
  const float* wv  = (const float*)d_in[3];
  const float* lq1 = (const float*)d_in[4];
  const float* lq2 = (const float*)d_in[5];
  const float* lk1 = (const float*)d_in[6];
  const float* lk2 = (const float*)d_in[7];
  const float* rw  = (const float*)d_in[8];
  float* out = (float*)d_out;

  char* ws = (char*)d_ws;
  short* qm = (short*)(ws);                    // 2 MB (q pre-scaled 0.125)
  short* kb = (short*)(ws + (2u << 20));       // 2 MB
  short* vt = (short*)(ws + (4u << 20));       // 2 MB (V transposed [b][h][s])
  short* wc = (short*)(ws + (6u << 20));       // 1.5 MB
  float* ao = (float*)(ws + (8u << 20));       // 8 MB [2][8192][128]
  float* al = (float*)(ws + (16u << 20));      // 64 KB [2][8192]
  float* qa = (float*)(ws + (16u << 20) + 65536u);  // 12.6 MB [8192][384] fp32

  hipMemsetAsync(ws + (8u << 20), 0, 8388608u + 65536u + 12582912u, stream);

  convw_kernel<<<768, 256, 0, stream>>>(wq, wk, wv, wc);
  proj_kernel<<<1024, 256, 0, stream>>>(x, wc, qa);
  conv_qk_kernel<<<2048, 256, 0, stream>>>(qa, qm, kb);
  conv_v_kernel<<<1024, 256, 0, stream>>>(qa, vt);
  attn_kernel<<<512, 256, 0, stream>>>(qm, kb, vt, ao, al);
  merge_kernel<<<1024, 256, 0, stream>>>(ao, al, lq1, lq2, lk1, lk2, rw, out);
}

// Round 16
// 107.663 us; speedup vs baseline: 2.1475x; 1.3284x over previous
//
#include <hip/hip_runtime.h>
#include <hip/hip_bf16.h>
#include <math.h>

#define S_LEN 4096
#define DMODEL 2048
#define HEADD 128

typedef __attribute__((ext_vector_type(8))) short short8;
typedef __attribute__((ext_vector_type(4))) float floatx4;

__device__ __forceinline__ short f2bs(float f) {
  __hip_bfloat16 h = __float2bfloat16(f);
  short s; __builtin_memcpy(&s, &h, 2); return s;
}
__device__ __forceinline__ float bs2f(short s) {
  unsigned u = ((unsigned)(unsigned short)s) << 16;
  float f; __builtin_memcpy(&f, &u, 4); return f;
}
__device__ __forceinline__ int pkbf(float a, float b) {  // (lo=a, hi=b) bf16 pair
  return (int)(((unsigned)(unsigned short)f2bs(b) << 16) |
               (unsigned)(unsigned short)f2bs(a));
}

// ---- Kernel 1: convert Wq,Wk,Wv (fp32 [128][2048] each) -> wc bf16 [384][2048]
__global__ __launch_bounds__(256) void convw_kernel(const float* __restrict__ wq,
                                                    const float* __restrict__ wk,
                                                    const float* __restrict__ wv,
                                                    short* __restrict__ wc) {
  const int per = 128 * 2048;
  int e = (blockIdx.x * blockDim.x + threadIdx.x) * 4;
  const float* src = (e < per) ? wq : (e < 2 * per) ? wk : wv;
  int off = e & (per - 1);
  float4 v = *(const float4*)(src + off);
  short4 r;
  r.x = f2bs(v.x); r.y = f2bs(v.y); r.z = f2bs(v.z); r.w = f2bs(v.w);
  *(short4*)(wc + e) = r;
}

// ---- Kernel 2: projection GEMM, LDS-staged dbuf; kh-partials to qa0/qa1
// via PLAIN bf16 stores (no atomics, no memset). grid 1024 = 256mb x 2nb x 2kh.
__global__ __launch_bounds__(256, 4) void proj_kernel(const float* __restrict__ x,
                                                      const short* __restrict__ wc,
                                                      short* __restrict__ qa0,
                                                      short* __restrict__ qa1) {
  const int tid = threadIdx.x;
  const int w = tid >> 6;
  const int lane = tid & 63;
  const int lo = lane & 15, g = lane >> 4;
  const int id = blockIdx.x;
  const int mb = id & 255, nb = (id >> 8) & 1, kh = id >> 9;
  const int m0 = mb * 32;
  const int n0 = nb * 192;
  const int k0 = kh * 1024;
  short* qa = kh ? qa1 : qa0;

  __shared__ short xt[2][32][40];
  __shared__ short wt[2][192][40];

  const int xr = tid >> 3, xk = (tid & 7) * 4;
  const int wr = tid >> 2, wq4 = (tid & 3) * 8;
  const float* xsrc = x + (size_t)(m0 + xr) * DMODEL + k0 + xk;
  const short* wsrc = wc + (size_t)(n0 + wr) * DMODEL + k0 + wq4;

  const int mrow = (w >> 1) * 16;
  const int ncol = (w & 1) * 96;

  floatx4 acc[6];
#pragma unroll
  for (int t = 0; t < 6; ++t) acc[t] = floatx4{0.f, 0.f, 0.f, 0.f};

  {
    float4 xv = *(const float4*)(xsrc);
    short4 xs;
    xs.x = f2bs(xv.x); xs.y = f2bs(xv.y); xs.z = f2bs(xv.z); xs.w = f2bs(xv.w);
    *(short4*)(&xt[0][xr][xk]) = xs;
#pragma unroll
    for (int c = 0; c < 3; ++c) {
      int4 wv = *(const int4*)(wsrc + (size_t)c * 64 * DMODEL);
      *(int4*)(&wt[0][c * 64 + wr][wq4]) = wv;
    }
  }
  __syncthreads();

  int cur = 0;
#pragma unroll 1
  for (int it = 0; it < 32; ++it) {
    float4 xn;
    int4 wn0, wn1, wn2;
    if (it + 1 < 32) {
      const int kn = (it + 1) * 32;
      xn = *(const float4*)(xsrc + kn);
      wn0 = *(const int4*)(wsrc + kn);
      wn1 = *(const int4*)(wsrc + (size_t)64 * DMODEL + kn);
      wn2 = *(const int4*)(wsrc + (size_t)128 * DMODEL + kn);
    }

    short8 af = *(const short8*)(&xt[cur][mrow + lo][g * 8]);
#pragma unroll
    for (int t = 0; t < 6; ++t) {
      short8 bf = *(const short8*)(&wt[cur][ncol + t * 16 + lo][g * 8]);
      acc[t] = __builtin_amdgcn_mfma_f32_16x16x32_bf16(af, bf, acc[t], 0, 0, 0);
    }

    if (it + 1 < 32) {
      short4 xs;
      xs.x = f2bs(xn.x); xs.y = f2bs(xn.y); xs.z = f2bs(xn.z); xs.w = f2bs(xn.w);
      *(short4*)(&xt[cur ^ 1][xr][xk]) = xs;
      *(int4*)(&wt[cur ^ 1][0 * 64 + wr][wq4]) = wn0;
      *(int4*)(&wt[cur ^ 1][1 * 64 + wr][wq4]) = wn1;
      *(int4*)(&wt[cur ^ 1][2 * 64 + wr][wq4]) = wn2;
    }
    __syncthreads();
    cur ^= 1;
  }

  // plain bf16 partial stores
#pragma unroll
  for (int t = 0; t < 6; ++t) {
    int n = n0 + ncol + t * 16 + lo;
#pragma unroll
    for (int j = 0; j < 4; ++j) {
      int m = m0 + mrow + g * 4 + j;
      qa[(size_t)m * 384 + n] = f2bs(acc[t][j]);
    }
  }
}

// ---- Kernel 2b: qa0+qa1 cols 0..255 -> qm (scaled 0.125), kb
__global__ __launch_bounds__(256) void conv_qk_kernel(const short* __restrict__ qa0,
                                                      const short* __restrict__ qa1,
                                                      short* __restrict__ qm,
                                                      short* __restrict__ kb) {
  int e = (blockIdx.x * 256 + threadIdx.x) * 4;   // over [8192][256]
  int m = e >> 8, c = e & 255;
  short4 a = *(const short4*)(qa0 + (size_t)m * 384 + c);
  short4 b = *(const short4*)(qa1 + (size_t)m * 384 + c);
  float vx = bs2f(a.x) + bs2f(b.x);
  float vy = bs2f(a.y) + bs2f(b.y);
  float vz = bs2f(a.z) + bs2f(b.z);
  float vw = bs2f(a.w) + bs2f(b.w);
  short4 r;
  if (c < 128) {
    r.x = f2bs(vx * 0.125f); r.y = f2bs(vy * 0.125f);
    r.z = f2bs(vz * 0.125f); r.w = f2bs(vw * 0.125f);
    *(short4*)(qm + (size_t)m * 128 + c) = r;
  } else {
    r.x = f2bs(vx); r.y = f2bs(vy); r.z = f2bs(vz); r.w = f2bs(vw);
    *(short4*)(kb + (size_t)m * 128 + (c - 128)) = r;
  }
}

// ---- Kernel 2c: qa0+qa1 cols 256..383 -> vt[b][h][s] via LDS transpose
// grid 128 = 2b x 64 s-tiles of 64; coalesced reads AND writes.
// R15 BUG FIX: load loop was q<2 with stride 16 (covered only half the
// columns); now q<4 with stride 8 -> full contiguous 32-short coverage.
__global__ __launch_bounds__(256) void conv_v_kernel(const short* __restrict__ qa0,
                                                     const short* __restrict__ qa1,
                                                     short* __restrict__ vt) {
  const int tid = threadIdx.x;
  const int bb = blockIdx.x >> 6, st = blockIdx.x & 63;
  const int s0 = st * 64;

  __shared__ short ld[64][136];   // [s][h], pad 8

  const int r = tid >> 2, c8 = (tid & 3) * 32;
#pragma unroll
  for (int q = 0; q < 4; ++q) {
    const size_t off = (size_t)(bb * 4096 + s0 + r) * 384 + 256 + c8 + q * 8;
    short8 a = *(const short8*)(qa0 + off);
    short8 b = *(const short8*)(qa1 + off);
    short8 o;
#pragma unroll
    for (int i = 0; i < 8; ++i) o[i] = f2bs(bs2f(a[i]) + bs2f(b[i]));
    *(short8*)(&ld[r][c8 + q * 8]) = o;
  }
  __syncthreads();

  const int h = tid >> 1, sh = (tid & 1) * 32;
#pragma unroll
  for (int q = 0; q < 4; ++q) {
    short8 t;
#pragma unroll
    for (int i = 0; i < 8; ++i) t[i] = ld[sh + q * 8 + i][h];
    *(short8*)(vt + ((size_t)bb * 128 + h) * 4096 + s0 + sh + q * 8) = t;
  }
}

// ---- Kernel 3: LDS-staged flash attention -> plain bf16 partial stores
// grid 1024 = 128 qblk x 8 ksp (ksp = id&7 -> XCD owns one 512KB K/V slice).
// 16 iters of 32 kv. Epilogue: packed short8 stores to po in permuted col
// layout c' = lo*8+n (16B coalesced), pls plain stores. ZERO atomics.
__global__ __launch_bounds__(256, 3) void attn_kernel(const short* __restrict__ qm,
                                                      const short* __restrict__ kb,
                                                      const short* __restrict__ vt,
                                                      short* __restrict__ po,
                                                      float* __restrict__ pls) {
  const int tid = threadIdx.x;
  const int w = tid >> 6;
  const int lane = tid & 63;
  const int lo = lane & 15, g = lane >> 4;
  const int qsp = w >> 1;           // subtile pair 0/1
  const int s = w & 1;              // attn stream
  const int id = blockIdx.x;
  const int ksp = id & 7;           // kv eighth (512 kv, 16 steps) -> XCD pin
  const int qblk = id >> 3;         // 0..127 global (b = qblk>>6)
  const int b = qblk >> 6;
  const int kv_base = ksp * 512;

  __shared__ short kt[2][32 * 128];   // K tile, XOR-swizzled chunks
  __shared__ short vl[2][128 * 32];   // V^T tile, XOR-swizzled chunks

  const int kr0 = tid >> 4, kck = tid & 15;
  const int vr0 = tid >> 2, vck = tid & 3;
  const short* kS = kb + (size_t)b * S_LEN * HEADD;
  const short* vS = vt + (size_t)b * HEADD * S_LEN;
  const int kld0 = kr0 * 128 + ((kck ^ (kr0 & 7)) * 8);
  const int kld1 = (kr0 + 16) * 128 + ((kck ^ (kr0 & 7)) * 8);
  const int vld0 = vr0 * 32 + ((vck ^ (vr0 & 3)) * 8);
  const int vld1 = (vr0 + 64) * 32 + ((vck ^ (vr0 & 3)) * 8);

  const int rowqA = qblk * 64 + qsp * 32;
  const int rowqB = rowqA + 16;
  const short* qrowA = qm + (size_t)(rowqA + lo) * HEADD + s * 64;
  const short* qrowB = qm + (size_t)(rowqB + lo) * HEADD + s * 64;
  const short8 qA0 = *(const short8*)(qrowA + g * 8);
  const short8 qA1 = *(const short8*)(qrowA + 32 + g * 8);
  const short8 qB0 = *(const short8*)(qrowB + g * 8);
  const short8 qB1 = *(const short8*)(qrowB + 32 + g * 8);

  floatx4 accA[8], accB[8];
#pragma unroll
  for (int n = 0; n < 8; ++n) {
    accA[n] = floatx4{0.f, 0.f, 0.f, 0.f};
    accB[n] = floatx4{0.f, 0.f, 0.f, 0.f};
  }
  float lxA = 0.f, lxB = 0.f;

  const int kc0 = ((s * 8 + g) ^ (lo & 7)) * 8;
  const int kc1 = ((s * 8 + 4 + g) ^ (lo & 7)) * 8;
  const int kro0 = lo * 128, kro1 = (16 + lo) * 128;
  const int vco = (g ^ (lo & 3)) * 8;

  const int gA = (g & 1) * 2;
  const int idx0 = lo + 16 * gA, idx1 = idx0 + 16;
  const bool hi = (g >= 2);

  {
    int4 ka = *(const int4*)(kS + (size_t)(kv_base + kr0) * HEADD + kck * 8);
    int4 kbx = *(const int4*)(kS + (size_t)(kv_base + kr0 + 16) * HEADD + kck * 8);
    int4 va = *(const int4*)(vS + (size_t)vr0 * S_LEN + kv_base + vck * 8);
    int4 vb = *(const int4*)(vS + (size_t)(vr0 + 64) * S_LEN + kv_base + vck * 8);
    *(int4*)(&kt[0][kld0]) = ka;
    *(int4*)(&kt[0][kld1]) = kbx;
    *(int4*)(&vl[0][vld0]) = va;
    *(int4*)(&vl[0][vld1]) = vb;
  }
  __syncthreads();

  int cur = 0;
#pragma unroll 1
  for (int it = 0; it < 16; ++it) {
    int4 ka, kbx, va, vb;
    if (it + 1 < 16) {
      const int kvn = kv_base + (it + 1) * 32;
      ka  = *(const int4*)(kS + (size_t)(kvn + kr0) * HEADD + kck * 8);
      kbx = *(const int4*)(kS + (size_t)(kvn + kr0 + 16) * HEADD + kck * 8);
      va  = *(const int4*)(vS + (size_t)vr0 * S_LEN + kvn + vck * 8);
      vb  = *(const int4*)(vS + (size_t)(vr0 + 64) * S_LEN + kvn + vck * 8);
    }

    const short* kbase = &kt[cur][0];
    short8 a00 = *(const short8*)(kbase + kro0 + kc0);
    short8 a01 = *(const short8*)(kbase + kro0 + kc1);
    short8 a10 = *(const short8*)(kbase + kro1 + kc0);
    short8 a11 = *(const short8*)(kbase + kro1 + kc1);

    floatx4 z = floatx4{0.f, 0.f, 0.f, 0.f};
    floatx4 u;
    u = __builtin_amdgcn_mfma_f32_16x16x32_bf16(a00, qA0, z, 0, 0, 0);
    floatx4 T0A = __builtin_amdgcn_mfma_f32_16x16x32_bf16(a01, qA1, u, 0, 0, 0);
    u = __builtin_amdgcn_mfma_f32_16x16x32_bf16(a10, qA0, z, 0, 0, 0);
    floatx4 T1A = __builtin_amdgcn_mfma_f32_16x16x32_bf16(a11, qA1, u, 0, 0, 0);
    u = __builtin_amdgcn_mfma_f32_16x16x32_bf16(a00, qB0, z, 0, 0, 0);
    floatx4 T0B = __builtin_amdgcn_mfma_f32_16x16x32_bf16(a01, qB1, u, 0, 0, 0);
    u = __builtin_amdgcn_mfma_f32_16x16x32_bf16(a10, qB0, z, 0, 0, 0);
    floatx4 T1B = __builtin_amdgcn_mfma_f32_16x16x32_bf16(a11, qB1, u, 0, 0, 0);

    short8 paA, paB;
    {
      float p0 = __expf(T0A[0]), p1 = __expf(T0A[1]), p2 = __expf(T0A[2]), p3 = __expf(T0A[3]);
      float p4 = __expf(T1A[0]), p5 = __expf(T1A[1]), p6 = __expf(T1A[2]), p7 = __expf(T1A[3]);
      float lp = ((p0 + p1) + (p2 + p3)) + ((p4 + p5) + (p6 + p7));
      lp += __shfl_xor(lp, 16);
      lp += __shfl_xor(lp, 32);
      lxA += lp;
      int c00 = pkbf(p0, p1), c01 = pkbf(p2, p3);
      int c10 = pkbf(p4, p5), c11 = pkbf(p6, p7);
      int t0a = __shfl(c00, idx0), t0b = __shfl(c01, idx0);
      int t0c = __shfl(c00, idx1), t0d = __shfl(c01, idx1);
      int t1a = __shfl(c10, idx0), t1b = __shfl(c11, idx0);
      int t1c = __shfl(c10, idx1), t1d = __shfl(c11, idx1);
      int w0 = hi ? t1a : t0a, w1 = hi ? t1b : t0b;
      int w2 = hi ? t1c : t0c, w3 = hi ? t1d : t0d;
      int4 tmp = {w0, w1, w2, w3}; __builtin_memcpy(&paA, &tmp, 16);
    }
    {
      float p0 = __expf(T0B[0]), p1 = __expf(T0B[1]), p2 = __expf(T0B[2]), p3 = __expf(T0B[3]);
      float p4 = __expf(T1B[0]), p5 = __expf(T1B[1]), p6 = __expf(T1B[2]), p7 = __expf(T1B[3]);
      float lp = ((p0 + p1) + (p2 + p3)) + ((p4 + p5) + (p6 + p7));
      lp += __shfl_xor(lp, 16);
      lp += __shfl_xor(lp, 32);
      lxB += lp;
      int c00 = pkbf(p0, p1), c01 = pkbf(p2, p3);
      int c10 = pkbf(p4, p5), c11 = pkbf(p6, p7);
      int t0a = __shfl(c00, idx0), t0b = __shfl(c01, idx0);
      int t0c = __shfl(c00, idx1), t0d = __shfl(c01, idx1);
      int t1a = __shfl(c10, idx0), t1b = __shfl(c11, idx0);
      int t1c = __shfl(c10, idx1), t1d = __shfl(c11, idx1);
      int w0 = hi ? t1a : t0a, w1 = hi ? t1b : t0b;
      int w2 = hi ? t1c : t0c, w3 = hi ? t1d : t0d;
      int4 tmp = {w0, w1, w2, w3}; __builtin_memcpy(&paB, &tmp, 16);
    }

    const short* vbase = &vl[cur][0];
#pragma unroll
    for (int n = 0; n < 8; ++n) {
      short8 vf = *(const short8*)(vbase + (n * 16 + lo) * 32 + vco);
      accA[n] = __builtin_amdgcn_mfma_f32_16x16x32_bf16(paA, vf, accA[n], 0, 0, 0);
      accB[n] = __builtin_amdgcn_mfma_f32_16x16x32_bf16(paB, vf, accB[n], 0, 0, 0);
    }

    if (it + 1 < 16) {
      *(int4*)(&kt[cur ^ 1][kld0]) = ka;
      *(int4*)(&kt[cur ^ 1][kld1]) = kbx;
      *(int4*)(&vl[cur ^ 1][vld0]) = va;
      *(int4*)(&vl[cur ^ 1][vld1]) = vb;
    }
    __syncthreads();
    cur ^= 1;
  }

  // ---- packed bf16 partial stores (permuted cols c' = lo*8+n), no atomics ----
  short* pw = po + ((size_t)(ksp * 2 + s) * 8192) * 128;
#pragma unroll
  for (int j = 0; j < 4; ++j) {
    short8 pk;
#pragma unroll
    for (int n = 0; n < 8; ++n) pk[n] = f2bs(accA[n][j]);
    *(short8*)(pw + (size_t)(rowqA + g * 4 + j) * 128 + lo * 8) = pk;
#pragma unroll
    for (int n = 0; n < 8; ++n) pk[n] = f2bs(accB[n][j]);
    *(short8*)(pw + (size_t)(rowqB + g * 4 + j) * 128 + lo * 8) = pk;
  }
  if (g == 0) {
    pls[(size_t)(ksp * 2 + s) * 8192 + rowqA + lo] = lxA;
    pls[(size_t)(ksp * 2 + s) * 8192 + rowqB + lo] = lxB;
  }
}

// ---- Kernel 4: merge 8 ksp partials + diff combine + RMSNorm -> out
// grid 512 x 256 thr; thread = (row, lo): cols n*16+lo (stored at lo*8+n).
__global__ __launch_bounds__(256) void merge_kernel(const short* __restrict__ po,
                                                    const float* __restrict__ pls,
                                                    const float* __restrict__ lq1,
                                                    const float* __restrict__ lq2,
                                                    const float* __restrict__ lk1,
                                                    const float* __restrict__ lk2,
                                                    const float* __restrict__ rmsw,
                                                    float* __restrict__ out) {
  const int tid = threadIdx.x;
  const int row = blockIdx.x * 16 + (tid >> 4);
  const int lo = tid & 15;

  float a1s = 0.f, a2s = 0.f;
  for (int i = 0; i < 64; ++i) {
    a1s = fmaf(lq1[i], lk1[i], a1s);
    a2s = fmaf(lq2[i], lk2[i], a2s);
  }
  const float lam = __expf(a1s) - __expf(a2s) + 0.7836057665316245f;

  float o1[8], o2[8];
#pragma unroll
  for (int n = 0; n < 8; ++n) { o1[n] = 0.f; o2[n] = 0.f; }
  float l1 = 0.f, l2 = 0.f;
#pragma unroll
  for (int ksp = 0; ksp < 8; ++ksp) {
    short8 sa = *(const short8*)(po + ((size_t)(ksp * 2 + 0) * 8192 + row) * 128 + lo * 8);
    short8 sb = *(const short8*)(po + ((size_t)(ksp * 2 + 1) * 8192 + row) * 128 + lo * 8);
#pragma unroll
    for (int n = 0; n < 8; ++n) { o1[n] += bs2f(sa[n]); o2[n] += bs2f(sb[n]); }
    l1 += pls[(size_t)(ksp * 2 + 0) * 8192 + row];
    l2 += pls[(size_t)(ksp * 2 + 1) * 8192 + row];
  }
  const float iL1 = 1.f / l1, iL2 = 1.f / l2;

  float v[8];
  float ssq = 0.f;
#pragma unroll
  for (int n = 0; n < 8; ++n) {
    v[n] = o1[n] * iL1 - lam * (o2[n] * iL2);
    ssq += v[n] * v[n];
  }
  ssq += __shfl_xor(ssq, 1);
  ssq += __shfl_xor(ssq, 2);
  ssq += __shfl_xor(ssq, 4);
  ssq += __shfl_xor(ssq, 8);
  const float rr = rsqrtf(ssq * (1.f / 128.f) + 1.1920928955078125e-07f);

  float* ob = out + (size_t)row * 128;
#pragma unroll
  for (int n = 0; n < 8; ++n) {
    int c = n * 16 + lo;
    ob[c] = 0.21639423346837554f * v[n] * rr * rmsw[c];
  }
}

extern "C" void kernel_launch(void* const* d_in, const int* in_sizes, int n_in,
                              void* d_out, int out_size, void* d_ws, size_t ws_size,
                              hipStream_t stream) {
  const float* x   = (const float*)d_in[0];
  const float* wq  = (const float*)d_in[1];
  const float* wk  = (const float*)d_in[2];
  const float* wv  = (const float*)d_in[3];
  const float* lq1 = (const float*)d_in[4];
  const float* lq2 = (const float*)d_in[5];
  const float* lk1 = (const float*)d_in[6];
  const float* lk2 = (const float*)d_in[7];
  const float* rw  = (const float*)d_in[8];
  float* out = (float*)d_out;

  char* ws = (char*)d_ws;
  short* qm  = (short*)(ws);                        // 2 MB (q pre-scaled 0.125)
  short* kb  = (short*)(ws + (2u << 20));           // 2 MB
  short* vt  = (short*)(ws + (4u << 20));           // 2 MB (V^T [b][h][s])
  short* wc  = (short*)(ws + (6u << 20));           // 1.5 MB
  short* qa0 = (short*)(ws + (8u << 20));           // 6.3 MB bf16 [8192][384] (kh=0)
  short* qa1 = (short*)(ws + (8u << 20) + 6291456u);// 6.3 MB (kh=1)
  short* po  = (short*)(ws + (8u << 20));           // 32 MB bf16 [16][8192][128] (aliases qa)
  float* pls = (float*)(ws + (40u << 20));          // 512 KB fp32 [16][8192]

  convw_kernel<<<768, 256, 0, stream>>>(wq, wk, wv, wc);
  proj_kernel<<<1024, 256, 0, stream>>>(x, wc, qa0, qa1);
  conv_qk_kernel<<<2048, 256, 0, stream>>>(qa0, qa1, qm, kb);
  conv_v_kernel<<<128, 256, 0, stream>>>(qa0, qa1, vt);
  attn_kernel<<<1024, 256, 0, stream>>>(qm, kb, vt, po, pls);   // po overwrites qa region (dead)
  merge_kernel<<<512, 256, 0, stream>>>(po, pls, lq1, lq2, lk1, lk2, rw, out);
}

// Round 17
// 102.817 us; speedup vs baseline: 2.2487x; 1.0471x over previous
//
#include <hip/hip_runtime.h>
#include <hip/hip_bf16.h>
#include <math.h>

#define S_LEN 4096
#define DMODEL 2048
#define HEADD 128

typedef __attribute__((ext_vector_type(8))) short short8;
typedef __attribute__((ext_vector_type(4))) float floatx4;

__device__ __forceinline__ short f2bs(float f) {
  __hip_bfloat16 h = __float2bfloat16(f);
  short s; __builtin_memcpy(&s, &h, 2); return s;
}
__device__ __forceinline__ float bs2f(short s) {
  unsigned u = ((unsigned)(unsigned short)s) << 16;
  float f; __builtin_memcpy(&f, &u, 4); return f;
}
__device__ __forceinline__ int pkbf(float a, float b) {  // (lo=a, hi=b) bf16 pair
  return (int)(((unsigned)(unsigned short)f2bs(b) << 16) |
               (unsigned)(unsigned short)f2bs(a));
}

// ---- Kernel 1: convert Wq,Wk,Wv (fp32 [128][2048] each) -> wc bf16 [384][2048]
__global__ __launch_bounds__(256) void convw_kernel(const float* __restrict__ wq,
                                                    const float* __restrict__ wk,
                                                    const float* __restrict__ wv,
                                                    short* __restrict__ wc) {
  const int per = 128 * 2048;
  int e = (blockIdx.x * blockDim.x + threadIdx.x) * 4;
  const float* src = (e < per) ? wq : (e < 2 * per) ? wk : wv;
  int off = e & (per - 1);
  float4 v = *(const float4*)(src + off);
  short4 r;
  r.x = f2bs(v.x); r.y = f2bs(v.y); r.z = f2bs(v.z); r.w = f2bs(v.w);
  *(short4*)(wc + e) = r;
}

// ---- Kernel 2: projection GEMM, full-K blocks, 2-deep pipeline, swizzled LDS.
// grid 512 = 2 nb (HIGH bit: mb pair shares XCD) x 256 mb; 256 thr = 4 waves
// (m-sub x n-sub), wave = 16 rows x 96 cols, acc[6]. 64 k-steps of 32.
// LDS tiles packed [rows/2][64] shorts (2 rows / 128B line) + chunk XOR
// (cc ^= lr&7): all access patterns 2-way max (free). Register sets A/B
// alternate: tile it+2 loaded at iter top, LDS-written one iter later.
// Direct stores: qm (x0.125), kb, vstage (row-major). No atomics.
__global__ __launch_bounds__(256, 3) void proj_kernel(const float* __restrict__ x,
                                                      const short* __restrict__ wc,
                                                      short* __restrict__ qm,
                                                      short* __restrict__ kb,
                                                      short* __restrict__ vstage) {
  const int tid = threadIdx.x;
  const int w = tid >> 6;
  const int lane = tid & 63;
  const int lo = lane & 15, g = lane >> 4;
  const int id = blockIdx.x;
  const int nb = id >> 8, mb = id & 255;
  const int m0 = mb * 32;
  const int n0 = nb * 192;

  __shared__ short xt[2][16 * 64];   // X tile: 32 rows x 32 k (2 rows/line)
  __shared__ short wt[2][96 * 64];   // W tile: 192 rows x 32 k

  // staging: X by tid<128 (row xr, chunk xc); W by all (rows wr+{0,64,128}, chunk wq)
  const int xr = tid >> 2, xc = tid & 3;
  const bool doX = tid < 128;
  const float* xsrc = x + (size_t)(m0 + (doX ? xr : 0)) * DMODEL + xc * 8;
  const int xl = (xr >> 1) * 64 + ((((xr & 1) * 4 + xc) ^ ((xr >> 1) & 7)) * 8);
  const int wr = tid >> 2, wq = tid & 3;
  const short* wsrc = wc + (size_t)(n0 + wr) * DMODEL + wq * 8;
  int wl0, wl1, wl2;
  {
    int R0 = wr, R1 = 64 + wr, R2 = 128 + wr;
    wl0 = (R0 >> 1) * 64 + ((((R0 & 1) * 4 + wq) ^ ((R0 >> 1) & 7)) * 8);
    wl1 = (R1 >> 1) * 64 + ((((R1 & 1) * 4 + wq) ^ ((R1 >> 1) & 7)) * 8);
    wl2 = (R2 >> 1) * 64 + ((((R2 & 1) * 4 + wq) ^ ((R2 >> 1) & 7)) * 8);
  }

  const int mrow = (w >> 1) * 16;
  const int ncol = (w & 1) * 96;
  int aoff;
  { int r = mrow + lo; aoff = (r >> 1) * 64 + ((((r & 1) * 4 + g) ^ ((r >> 1) & 7)) * 8); }
  int boff[6];
#pragma unroll
  for (int t = 0; t < 6; ++t) {
    int R = ncol + t * 16 + lo;
    boff[t] = (R >> 1) * 64 + ((((R & 1) * 4 + g) ^ ((R >> 1) & 7)) * 8);
  }

  floatx4 acc[6];
#pragma unroll
  for (int t = 0; t < 6; ++t) acc[t] = floatx4{0.f, 0.f, 0.f, 0.f};

  float4 xa0, xa1, xb0, xb1;
  int4 wa0, wa1, wa2, wb0, wb1, wb2;

  // prologue: tile0 -> A -> LDS[0]; tile1 -> B (in flight)
  if (doX) { xa0 = *(const float4*)(xsrc); xa1 = *(const float4*)(xsrc + 4); }
  wa0 = *(const int4*)(wsrc);
  wa1 = *(const int4*)(wsrc + (size_t)64 * DMODEL);
  wa2 = *(const int4*)(wsrc + (size_t)128 * DMODEL);
  if (doX) {
    short8 xs;
    xs[0] = f2bs(xa0.x); xs[1] = f2bs(xa0.y); xs[2] = f2bs(xa0.z); xs[3] = f2bs(xa0.w);
    xs[4] = f2bs(xa1.x); xs[5] = f2bs(xa1.y); xs[6] = f2bs(xa1.z); xs[7] = f2bs(xa1.w);
    *(short8*)&xt[0][xl] = xs;
  }
  *(int4*)&wt[0][wl0] = wa0;
  *(int4*)&wt[0][wl1] = wa1;
  *(int4*)&wt[0][wl2] = wa2;
  if (doX) { xb0 = *(const float4*)(xsrc + 32); xb1 = *(const float4*)(xsrc + 36); }
  wb0 = *(const int4*)(wsrc + 32);
  wb1 = *(const int4*)(wsrc + (size_t)64 * DMODEL + 32);
  wb2 = *(const int4*)(wsrc + (size_t)128 * DMODEL + 32);
  __syncthreads();

#pragma unroll 1
  for (int it = 0; it < 64; it += 2) {
    // even: load A <- tile it+2; compute LDS[0] (tile it); write B -> LDS[1]
    if (it + 2 < 64) {
      const int k = (it + 2) * 32;
      if (doX) { xa0 = *(const float4*)(xsrc + k); xa1 = *(const float4*)(xsrc + k + 4); }
      wa0 = *(const int4*)(wsrc + k);
      wa1 = *(const int4*)(wsrc + (size_t)64 * DMODEL + k);
      wa2 = *(const int4*)(wsrc + (size_t)128 * DMODEL + k);
    }
    {
      short8 af = *(const short8*)&xt[0][aoff];
#pragma unroll
      for (int t = 0; t < 6; ++t) {
        short8 bf = *(const short8*)&wt[0][boff[t]];
        acc[t] = __builtin_amdgcn_mfma_f32_16x16x32_bf16(af, bf, acc[t], 0, 0, 0);
      }
    }
    if (doX) {
      short8 xs;
      xs[0] = f2bs(xb0.x); xs[1] = f2bs(xb0.y); xs[2] = f2bs(xb0.z); xs[3] = f2bs(xb0.w);
      xs[4] = f2bs(xb1.x); xs[5] = f2bs(xb1.y); xs[6] = f2bs(xb1.z); xs[7] = f2bs(xb1.w);
      *(short8*)&xt[1][xl] = xs;
    }
    *(int4*)&wt[1][wl0] = wb0;
    *(int4*)&wt[1][wl1] = wb1;
    *(int4*)&wt[1][wl2] = wb2;
    __syncthreads();

    // odd: load B <- tile it+3; compute LDS[1] (tile it+1); write A -> LDS[0]
    if (it + 3 < 64) {
      const int k = (it + 3) * 32;
      if (doX) { xb0 = *(const float4*)(xsrc + k); xb1 = *(const float4*)(xsrc + k + 4); }
      wb0 = *(const int4*)(wsrc + k);
      wb1 = *(const int4*)(wsrc + (size_t)64 * DMODEL + k);
      wb2 = *(const int4*)(wsrc + (size_t)128 * DMODEL + k);
    }
    {
      short8 af = *(const short8*)&xt[1][aoff];
#pragma unroll
      for (int t = 0; t < 6; ++t) {
        short8 bf = *(const short8*)&wt[1][boff[t]];
        acc[t] = __builtin_amdgcn_mfma_f32_16x16x32_bf16(af, bf, acc[t], 0, 0, 0);
      }
    }
    if (it + 2 < 64) {
      if (doX) {
        short8 xs;
        xs[0] = f2bs(xa0.x); xs[1] = f2bs(xa0.y); xs[2] = f2bs(xa0.z); xs[3] = f2bs(xa0.w);
        xs[4] = f2bs(xa1.x); xs[5] = f2bs(xa1.y); xs[6] = f2bs(xa1.z); xs[7] = f2bs(xa1.w);
        *(short8*)&xt[0][xl] = xs;
      }
      *(int4*)&wt[0][wl0] = wa0;
      *(int4*)&wt[0][wl1] = wa1;
      *(int4*)&wt[0][wl2] = wa2;
    }
    __syncthreads();
  }

  // direct stores: q scaled, k, vstage (row-major [8192][128])
#pragma unroll
  for (int t = 0; t < 6; ++t) {
    int n = n0 + ncol + t * 16 + lo;
#pragma unroll
    for (int j = 0; j < 4; ++j) {
      int m = m0 + mrow + g * 4 + j;
      float v = acc[t][j];
      if (n < HEADD) {
        qm[(size_t)m * HEADD + n] = f2bs(v * 0.125f);   // fold 1/sqrt(64)
      } else if (n < 2 * HEADD) {
        kb[(size_t)m * HEADD + (n - HEADD)] = f2bs(v);
      } else {
        vstage[(size_t)m * HEADD + (n - 2 * HEADD)] = f2bs(v);
      }
    }
  }
}

// ---- Kernel 2c: vstage[8192][128] -> vt[b][h][s] via LDS transpose
__global__ __launch_bounds__(256) void conv_v_kernel(const short* __restrict__ vstage,
                                                     short* __restrict__ vt) {
  const int tid = threadIdx.x;
  const int bb = blockIdx.x >> 6, st = blockIdx.x & 63;
  const int s0 = st * 64;

  __shared__ short ld[64][136];   // [s][h], pad 8

  const int r = tid >> 2, c8 = (tid & 3) * 32;
#pragma unroll
  for (int q = 0; q < 4; ++q) {
    const size_t off = (size_t)(bb * 4096 + s0 + r) * 128 + c8 + q * 8;
    *(short8*)(&ld[r][c8 + q * 8]) = *(const short8*)(vstage + off);
  }
  __syncthreads();

  const int h = tid >> 1, sh = (tid & 1) * 32;
#pragma unroll
  for (int q = 0; q < 4; ++q) {
    short8 t;
#pragma unroll
    for (int i = 0; i < 8; ++i) t[i] = ld[sh + q * 8 + i][h];
    *(short8*)(vt + ((size_t)bb * 128 + h) * 4096 + s0 + sh + q * 8) = t;
  }
}

// ---- Kernel 3: LDS-staged flash attention -> plain bf16 partial stores
// (unchanged from R16: grid 1024 = 128 qblk x 8 ksp, XOR-swizzled tiles,
// 2 q-subtiles/wave, zero atomics)
__global__ __launch_bounds__(256, 3) void attn_kernel(const short* __restrict__ qm,
                                                      const short* __restrict__ kb,
                                                      const short* __restrict__ vt,
                                                      short* __restrict__ po,
                                                      float* __restrict__ pls) {
  const int tid = threadIdx.x;
  const int w = tid >> 6;
  const int lane = tid & 63;
  const int lo = lane & 15, g = lane >> 4;
  const int qsp = w >> 1;
  const int s = w & 1;
  const int id = blockIdx.x;
  const int ksp = id & 7;
  const int qblk = id >> 3;
  const int b = qblk >> 6;
  const int kv_base = ksp * 512;

  __shared__ short kt[2][32 * 128];
  __shared__ short vl[2][128 * 32];

  const int kr0 = tid >> 4, kck = tid & 15;
  const int vr0 = tid >> 2, vck = tid & 3;
  const short* kS = kb + (size_t)b * S_LEN * HEADD;
  const short* vS = vt + (size_t)b * HEADD * S_LEN;
  const int kld0 = kr0 * 128 + ((kck ^ (kr0 & 7)) * 8);
  const int kld1 = (kr0 + 16) * 128 + ((kck ^ (kr0 & 7)) * 8);
  const int vld0 = vr0 * 32 + ((vck ^ (vr0 & 3)) * 8);
  const int vld1 = (vr0 + 64) * 32 + ((vck ^ (vr0 & 3)) * 8);

  const int rowqA = qblk * 64 + qsp * 32;
  const int rowqB = rowqA + 16;
  const short* qrowA = qm + (size_t)(rowqA + lo) * HEADD + s * 64;
  const short* qrowB = qm + (size_t)(rowqB + lo) * HEADD + s * 64;
  const short8 qA0 = *(const short8*)(qrowA + g * 8);
  const short8 qA1 = *(const short8*)(qrowA + 32 + g * 8);
  const short8 qB0 = *(const short8*)(qrowB + g * 8);
  const short8 qB1 = *(const short8*)(qrowB + 32 + g * 8);

  floatx4 accA[8], accB[8];
#pragma unroll
  for (int n = 0; n < 8; ++n) {
    accA[n] = floatx4{0.f, 0.f, 0.f, 0.f};
    accB[n] = floatx4{0.f, 0.f, 0.f, 0.f};
  }
  float lxA = 0.f, lxB = 0.f;

  const int kc0 = ((s * 8 + g) ^ (lo & 7)) * 8;
  const int kc1 = ((s * 8 + 4 + g) ^ (lo & 7)) * 8;
  const int kro0 = lo * 128, kro1 = (16 + lo) * 128;
  const int vco = (g ^ (lo & 3)) * 8;

  const int gA = (g & 1) * 2;
  const int idx0 = lo + 16 * gA, idx1 = idx0 + 16;
  const bool hi = (g >= 2);

  {
    int4 ka = *(const int4*)(kS + (size_t)(kv_base + kr0) * HEADD + kck * 8);
    int4 kbx = *(const int4*)(kS + (size_t)(kv_base + kr0 + 16) * HEADD + kck * 8);
    int4 va = *(const int4*)(vS + (size_t)vr0 * S_LEN + kv_base + vck * 8);
    int4 vb = *(const int4*)(vS + (size_t)(vr0 + 64) * S_LEN + kv_base + vck * 8);
    *(int4*)(&kt[0][kld0]) = ka;
    *(int4*)(&kt[0][kld1]) = kbx;
    *(int4*)(&vl[0][vld0]) = va;
    *(int4*)(&vl[0][vld1]) = vb;
  }
  __syncthreads();

  int cur = 0;
#pragma unroll 1
  for (int it = 0; it < 16; ++it) {
    int4 ka, kbx, va, vb;
    if (it + 1 < 16) {
      const int kvn = kv_base + (it + 1) * 32;
      ka  = *(const int4*)(kS + (size_t)(kvn + kr0) * HEADD + kck * 8);
      kbx = *(const int4*)(kS + (size_t)(kvn + kr0 + 16) * HEADD + kck * 8);
      va  = *(const int4*)(vS + (size_t)vr0 * S_LEN + kvn + vck * 8);
      vb  = *(const int4*)(vS + (size_t)(vr0 + 64) * S_LEN + kvn + vck * 8);
    }

    const short* kbase = &kt[cur][0];
    short8 a00 = *(const short8*)(kbase + kro0 + kc0);
    short8 a01 = *(const short8*)(kbase + kro0 + kc1);
    short8 a10 = *(const short8*)(kbase + kro1 + kc0);
    short8 a11 = *(const short8*)(kbase + kro1 + kc1);

    floatx4 z = floatx4{0.f, 0.f, 0.f, 0.f};
    floatx4 u;
    u = __builtin_amdgcn_mfma_f32_16x16x32_bf16(a00, qA0, z, 0, 0, 0);
    floatx4 T0A = __builtin_amdgcn_mfma_f32_16x16x32_bf16(a01, qA1, u, 0, 0, 0);
    u = __builtin_amdgcn_mfma_f32_16x16x32_bf16(a10, qA0, z, 0, 0, 0);
    floatx4 T1A = __builtin_amdgcn_mfma_f32_16x16x32_bf16(a11, qA1, u, 0, 0, 0);
    u = __builtin_amdgcn_mfma_f32_16x16x32_bf16(a00, qB0, z, 0, 0, 0);
    floatx4 T0B = __builtin_amdgcn_mfma_f32_16x16x32_bf16(a01, qB1, u, 0, 0, 0);
    u = __builtin_amdgcn_mfma_f32_16x16x32_bf16(a10, qB0, z, 0, 0, 0);
    floatx4 T1B = __builtin_amdgcn_mfma_f32_16x16x32_bf16(a11, qB1, u, 0, 0, 0);

    short8 paA, paB;
    {
      float p0 = __expf(T0A[0]), p1 = __expf(T0A[1]), p2 = __expf(T0A[2]), p3 = __expf(T0A[3]);
      float p4 = __expf(T1A[0]), p5 = __expf(T1A[1]), p6 = __expf(T1A[2]), p7 = __expf(T1A[3]);
      float lp = ((p0 + p1) + (p2 + p3)) + ((p4 + p5) + (p6 + p7));
      lp += __shfl_xor(lp, 16);
      lp += __shfl_xor(lp, 32);
      lxA += lp;
      int c00 = pkbf(p0, p1), c01 = pkbf(p2, p3);
      int c10 = pkbf(p4, p5), c11 = pkbf(p6, p7);
      int t0a = __shfl(c00, idx0), t0b = __shfl(c01, idx0);
      int t0c = __shfl(c00, idx1), t0d = __shfl(c01, idx1);
      int t1a = __shfl(c10, idx0), t1b = __shfl(c11, idx0);
      int t1c = __shfl(c10, idx1), t1d = __shfl(c11, idx1);
      int w0 = hi ? t1a : t0a, w1 = hi ? t1b : t0b;
      int w2 = hi ? t1c : t0c, w3 = hi ? t1d : t0d;
      int4 tmp = {w0, w1, w2, w3}; __builtin_memcpy(&paA, &tmp, 16);
    }
    {
      float p0 = __expf(T0B[0]), p1 = __expf(T0B[1]), p2 = __expf(T0B[2]), p3 = __expf(T0B[3]);
      float p4 = __expf(T1B[0]), p5 = __expf(T1B[1]), p6 = __expf(T1B[2]), p7 = __expf(T1B[3]);
      float lp = ((p0 + p1) + (p2 + p3)) + ((p4 + p5) + (p6 + p7));
      lp += __shfl_xor(lp, 16);
      lp += __shfl_xor(lp, 32);
      lxB += lp;
      int c00 = pkbf(p0, p1), c01 = pkbf(p2, p3);
      int c10 = pkbf(p4, p5), c11 = pkbf(p6, p7);
      int t0a = __shfl(c00, idx0), t0b = __shfl(c01, idx0);
      int t0c = __shfl(c00, idx1), t0d = __shfl(c01, idx1);
      int t1a = __shfl(c10, idx0), t1b = __shfl(c11, idx0);
      int t1c = __shfl(c10, idx1), t1d = __shfl(c11, idx1);
      int w0 = hi ? t1a : t0a, w1 = hi ? t1b : t0b;
      int w2 = hi ? t1c : t0c, w3 = hi ? t1d : t0d;
      int4 tmp = {w0, w1, w2, w3}; __builtin_memcpy(&paB, &tmp, 16);
    }

    const short* vbase = &vl[cur][0];
#pragma unroll
    for (int n = 0; n < 8; ++n) {
      short8 vf = *(const short8*)(vbase + (n * 16 + lo) * 32 + vco);
      accA[n] = __builtin_amdgcn_mfma_f32_16x16x32_bf16(paA, vf, accA[n], 0, 0, 0);
      accB[n] = __builtin_amdgcn_mfma_f32_16x16x32_bf16(paB, vf, accB[n], 0, 0, 0);
    }

    if (it + 1 < 16) {
      *(int4*)(&kt[cur ^ 1][kld0]) = ka;
      *(int4*)(&kt[cur ^ 1][kld1]) = kbx;
      *(int4*)(&vl[cur ^ 1][vld0]) = va;
      *(int4*)(&vl[cur ^ 1][vld1]) = vb;
    }
    __syncthreads();
    cur ^= 1;
  }

  short* pw = po + ((size_t)(ksp * 2 + s) * 8192) * 128;
#pragma unroll
  for (int j = 0; j < 4; ++j) {
    short8 pk;
#pragma unroll
    for (int n = 0; n < 8; ++n) pk[n] = f2bs(accA[n][j]);
    *(short8*)(pw + (size_t)(rowqA + g * 4 + j) * 128 + lo * 8) = pk;
#pragma unroll
    for (int n = 0; n < 8; ++n) pk[n] = f2bs(accB[n][j]);
    *(short8*)(pw + (size_t)(rowqB + g * 4 + j) * 128 + lo * 8) = pk;
  }
  if (g == 0) {
    pls[(size_t)(ksp * 2 + s) * 8192 + rowqA + lo] = lxA;
    pls[(size_t)(ksp * 2 + s) * 8192 + rowqB + lo] = lxB;
  }
}

// ---- Kernel 4: merge 8 ksp partials + diff combine + RMSNorm -> out (unchanged)
__global__ __launch_bounds__(256) void merge_kernel(const short* __restrict__ po,
                                                    const float* __restrict__ pls,
                                                    const float* __restrict__ lq1,
                                                    const float* __restrict__ lq2,
                                                    const float* __restrict__ lk1,
                                                    const float* __restrict__ lk2,
                                                    const float* __restrict__ rmsw,
                                                    float* __restrict__ out) {
  const int tid = threadIdx.x;
  const int row = blockIdx.x * 16 + (tid >> 4);
  const int lo = tid & 15;

  float a1s = 0.f, a2s = 0.f;
  for (int i = 0; i < 64; ++i) {
    a1s = fmaf(lq1[i], lk1[i], a1s);
    a2s = fmaf(lq2[i], lk2[i], a2s);
  }
  const float lam = __expf(a1s) - __expf(a2s) + 0.7836057665316245f;

  float o1[8], o2[8];
#pragma unroll
  for (int n = 0; n < 8; ++n) { o1[n] = 0.f; o2[n] = 0.f; }
  float l1 = 0.f, l2 = 0.f;
#pragma unroll
  for (int ksp = 0; ksp < 8; ++ksp) {
    short8 sa = *(const short8*)(po + ((size_t)(ksp * 2 + 0) * 8192 + row) * 128 + lo * 8);
    short8 sb = *(const short8*)(po + ((size_t)(ksp * 2 + 1) * 8192 + row) * 128 + lo * 8);
#pragma unroll
    for (int n = 0; n < 8; ++n) { o1[n] += bs2f(sa[n]); o2[n] += bs2f(sb[n]); }
    l1 += pls[(size_t)(ksp * 2 + 0) * 8192 + row];
    l2 += pls[(size_t)(ksp * 2 + 1) * 8192 + row];
  }
  const float iL1 = 1.f / l1, iL2 = 1.f / l2;

  float v[8];
  float ssq = 0.f;
#pragma unroll
  for (int n = 0; n < 8; ++n) {
    v[n] = o1[n] * iL1 - lam * (o2[n] * iL2);
    ssq += v[n] * v[n];
  }
  ssq += __shfl_xor(ssq, 1);
  ssq += __shfl_xor(ssq, 2);
  ssq += __shfl_xor(ssq, 4);
  ssq += __shfl_xor(ssq, 8);
  const float rr = rsqrtf(ssq * (1.f / 128.f) + 1.1920928955078125e-07f);

  float* ob = out + (size_t)row * 128;
#pragma unroll
  for (int n = 0; n < 8; ++n) {
    int c = n * 16 + lo;
    ob[c] = 0.21639423346837554f * v[n] * rr * rmsw[c];
  }
}

extern "C" void kernel_launch(void* const* d_in, const int* in_sizes, int n_in,
                              void* d_out, int out_size, void* d_ws, size_t ws_size,
                              hipStream_t stream) {
  const float* x   = (const float*)d_in[0];
  const float* wq  = (const float*)d_in[1];
  const float* wk  = (const float*)d_in[2];
  const float* wv  = (const float*)d_in[3];
  const float* lq1 = (const float*)d_in[4];
  const float* lq2 = (const float*)d_in[5];
  const float* lk1 = (const float*)d_in[6];
  const float* lk2 = (const float*)d_in[7];
  const float* rw  = (const float*)d_in[8];
  float* out = (float*)d_out;

  char* ws = (char*)d_ws;
  short* qm  = (short*)(ws);                        // 2 MB (q pre-scaled 0.125)
  short* kb  = (short*)(ws + (2u << 20));           // 2 MB
  short* vt  = (short*)(ws + (4u << 20));           // 2 MB (V^T [b][h][s])
  short* wc  = (short*)(ws + (6u << 20));           // 1.5 MB
  short* vstage = (short*)(ws + (6u << 20) + 1572864u); // 2 MB [8192][128] (7.5-9.5MB)
  short* po  = (short*)(ws + (8u << 20));           // 32 MB [16][8192][128] (vstage dead by then)
  float* pls = (float*)(ws + (40u << 20));          // 512 KB fp32 [16][8192]

  convw_kernel<<<768, 256, 0, stream>>>(wq, wk, wv, wc);
  proj_kernel<<<512, 256, 0, stream>>>(x, wc, qm, kb, vstage);
  conv_v_kernel<<<128, 256, 0, stream>>>(vstage, vt);
  attn_kernel<<<1024, 256, 0, stream>>>(qm, kb, vt, po, pls);
  merge_kernel<<<512, 256, 0, stream>>>(po, pls, lq1, lq2, lk1, lk2, rw, out);
}